// Round 12
// baseline (1537.493 us; speedup 1.0000x reference)
//
#include <hip/hip_runtime.h>
#include <hip/hip_bf16.h>
#include <math.h>

#define TPB 512

typedef __attribute__((ext_vector_type(8))) short bf16x8;
typedef __attribute__((ext_vector_type(4))) float f32x4;
typedef unsigned short u16;

#define MFMA(a, b, c) __builtin_amdgcn_mfma_f32_16x16x32_bf16(a, b, c, 0, 0, 0)
#define PRIO1 __builtin_amdgcn_s_setprio(1)
#define PRIO0 __builtin_amdgcn_s_setprio(0)

__device__ __forceinline__ u16 f2bf(float f) {   // native HW convert (R10/R11-validated)
  __hip_bfloat16 h = __float2bfloat16(f);
  return *reinterpret_cast<u16*>(&h);
}
__device__ __forceinline__ float bf2f(u16 h) {
  union { unsigned u; float f; } v; v.u = ((unsigned)h) << 16; return v.f;
}
__device__ __forceinline__ unsigned cvt2(float a0, float a1) {
  return (unsigned)f2bf(a0) | ((unsigned)f2bf(a1) << 16);
}
__device__ __forceinline__ void cvt4u(float a0, float a1, float a2, float a3, u16 o[4]) {
  o[0] = f2bf(a0); o[1] = f2bf(a1); o[2] = f2bf(a2); o[3] = f2bf(a3);
}

// fragment from LDS bf16 [row][pitch]: lane row = row0+(lane&15), k = kb+(lane>>4)*8+j
__device__ __forceinline__ bf16x8 fragL(const u16* B, int row0, int pitch, int kb, int lane) {
  return *(const bf16x8*)(B + (row0 + (lane & 15)) * pitch + kb + ((lane >> 4) << 3));
}
// fragment from global fp32 [row][stride] with on-the-fly bf16 convert (fallback)
__device__ __forceinline__ bf16x8 fragG(const float* __restrict__ W, int row0, int stride,
                                        int kb, int lane) {
  const float* p = W + (size_t)(row0 + (lane & 15)) * stride + kb + ((lane >> 4) << 3);
  float4 a = *(const float4*)p, b = *(const float4*)(p + 4);
  bf16x8 r;
  r[0] = (short)f2bf(a.x); r[1] = (short)f2bf(a.y); r[2] = (short)f2bf(a.z); r[3] = (short)f2bf(a.w);
  r[4] = (short)f2bf(b.x); r[5] = (short)f2bf(b.y); r[6] = (short)f2bf(b.z); r[7] = (short)f2bf(b.w);
  return r;
}
template<int PREW>
__device__ __forceinline__ bf16x8 wfrag(const float* __restrict__ Wg,
                                        const u16* __restrict__ Wp,
                                        int m, int f, int kh, int lane) {
  if constexpr (PREW)
    return *(const bf16x8*)(Wp + (size_t)m * 4096 + f * 1024 + kh * 512 + lane * 8);
  else
    return fragG(Wg, f * 16, 64, kh * 32, lane);
}

// prep: 0..11 encoder weights -> frag layout; 12 = adj2 frags; 13..140 = x transpose + dt
__global__ __launch_bounds__(256)
void prep_kernel(const float* __restrict__ t_inw, const float* __restrict__ t_ow,
                 const float* __restrict__ t_w1, const float* __restrict__ t_w2,
                 const float* __restrict__ adj, const float* __restrict__ x,
                 u16* __restrict__ wp, u16* __restrict__ wpA2,
                 float* __restrict__ wsDT, u16* __restrict__ wsX) {
  int m = blockIdx.x;
  if (m == 12) {
    __shared__ float a2[4096];
    for (int e = threadIdx.x; e < 4096; e += 256) {
      int w = e >> 6, u = e & 63;
      float sum = 0.f;
      for (int v = 0; v < 64; ++v) sum += adj[w * 64 + v] * adj[v * 64 + u];
      a2[e] = sum;
    }
    __syncthreads();
    for (int t = threadIdx.x; t < 4096; t += 256) {
      int j = t & 7, ln = (t >> 3) & 63, kh = (t >> 9) & 1, f = t >> 10;
      int row = f * 16 + (ln & 15);
      int k = kh * 32 + ((ln >> 4) << 3) + j;
      wpA2[t] = f2bf(a2[row * 64 + k]);
    }
    return;
  }
  if (m >= 13) {
    int b = m - 13;
    const float* times = x + ((size_t)b * 3 + 2) * 64 * 96;
    for (int i = threadIdx.x; i < 96 * 256; i += 256) {
      int s = i >> 8, idx = i & 255, f = idx >> 6, n = idx & 63;
      float v;
      if (f < 3) v = x[(((size_t)b * 3 + f) * 64 + n) * 96 + s];
      else {
        float dt = s ? (times[s] - times[s - 1]) : 0.f;
        v = dt;
        if (n == 0) wsDT[b * 96 + s] = dt;
      }
      wsX[((size_t)b * 96 + s) * 256 + idx] = f2bf(v);
    }
    return;
  }
  int l = m / 6, r = m % 6;
  const float* W;
  if (r < 3)       W = t_inw + l * 12288 + r * 4096;
  else if (r == 3) W = t_ow + l * 4096;
  else if (r == 4) W = t_w1 + l * 4096;
  else             W = t_w2 + l * 4096;
  for (int t = threadIdx.x; t < 4096; t += 256) {
    int j = t & 7, ln = (t >> 3) & 63, kh = (t >> 9) & 1, f = t >> 10;
    int row = f * 16 + (ln & 15);
    int k = kh * 32 + ((ln >> 4) << 3) + j;
    wp[(size_t)m * 4096 + t] = f2bf(W[row * 64 + k]);
  }
}

// ============ FAST KERNEL: R11 structure + setprio + early x-load ============
__global__ __launch_bounds__(TPB, 2)
void gcrnn_fast(const float* __restrict__ adj,
                const float* __restrict__ h0,
                const float* __restrict__ t_inb, const float* __restrict__ t_ob,
                const float* __restrict__ t_b1,  const float* __restrict__ t_b2,
                const float* __restrict__ t_g1,  const float* __restrict__ t_be1,
                const float* __restrict__ t_g2,  const float* __restrict__ t_be2,
                const float* __restrict__ uw,    const float* __restrict__ ub,
                const float* __restrict__ cw,    const float* __restrict__ cb,
                const u16* __restrict__ wsW,  const u16* __restrict__ wsA2,
                const float* __restrict__ wsDT, const u16* __restrict__ wsX,
                float* __restrict__ wsOut)
{
  const int b = blockIdx.x;
  const int tid = threadIdx.x;
  const int wv = tid >> 6;          // 0..7
  const int lane = tid & 63;
  const int lx = lane & 15;
  const int gq = (lane >> 4) << 2;  // 0,4,8,12
  const int rs = wv & 3;            // row stripe
  const int of0 = (wv >> 2) * 2;    // owned col-frag pair base {0,2}
  const int fA = wv >> 2;           // Q/K col-frag set {fA, fA+2}

  __shared__ __align__(16) u16 adjB[64 * 72];           //  9216 B
  __shared__ __align__(16) u16 Y0[64 * 72];             //  9216 B (attn input / h^T)
  __shared__ __align__(16) u16 Y1[64 * 72];             //  9216 B (LN1 output)
  __shared__ __align__(16) u16 Qb[64 * 72];             //  9216
  __shared__ __align__(16) u16 Kb[64 * 72];             //  9216
  __shared__ __align__(16) u16 VTb[64 * 72];            //  9216
  __shared__ __align__(16) u16 Pb[64 * 72];             //  9216
  __shared__ __align__(16) u16 xgB[80 * 72];            // 11520 (rows 68..79 zero)
  __shared__ __align__(16) u16 zTB[64 * 232];           // 29696 (cols 204..231 zero)
  __shared__ __align__(16) u16 uwcwB[2 * 4 * 7 * 512];  // 57344
  // total 163072 B

  // ---- one-time init ----
  float hreg[2][4];   // h[o][n]: o=(of0+ff)*16+lx, n=rs*16+gq+j
  {
    const int nb = rs * 16 + gq;
#pragma unroll
    for (int ff = 0; ff < 2; ++ff) {
      int o = (of0 + ff) * 16 + lx;
      float4 hv = *(const float4*)(h0 + (size_t)b * 4096 + o * 64 + nb);
#pragma unroll
      for (int j = 0; j < 4; ++j) {
        hreg[ff][j] = (&hv.x)[j];
        Y0[(nb + j) * 72 + o] = f2bf(hreg[ff][j]);
      }
    }
  }
  for (int i = tid; i < 4096; i += TPB)
    adjB[(i >> 6) * 72 + (i & 63)] = f2bf(adj[i]);
  for (int i = tid; i < 2 * 4 * 7 * 512; i += TPB) {
    int t = i;
    int j = t & 7; t >>= 3;
    int ln = t & 63; t >>= 6;
    int kh = t % 7; t /= 7;
    int f = t & 3; int mat = t >> 2;
    int o = f * 16 + (ln & 15);
    int k = kh * 32 + ((ln >> 4) << 3) + j;
    const float* W = mat ? cw : uw;
    uwcwB[i] = (k < 204) ? f2bf(W[o * 204 + k]) : (u16)0;
  }
  for (int i = tid; i < 64 * 28; i += TPB)
    zTB[(i / 28) * 232 + 204 + (i % 28)] = 0;
  for (int i = tid; i < 12 * 72; i += TPB)
    xgB[68 * 72 + i] = 0;
  __syncthreads();

  const float buo = ub[of0 * 16 + lx], buo2 = ub[(of0 + 1) * 16 + lx];
  const float bco = cb[of0 * 16 + lx], bco2 = cb[(of0 + 1) * 16 + lx];
  float hdreg[2][4];

  for (int s = 0; s < 96; ++s) {
    float dcur = wsDT[b * 96 + s];
    float sq1 = sqrtf(1.f - dcur), sq2 = sqrtf(dcur);

    for (int l = 0; l < 2; ++l) {
      const int l6 = l * 6;
      const float* inb = t_inb + l * 192;
      const float* ob  = t_ob  + l * 64;
      const float* bb1 = t_b1  + l * 64;
      const float* bb2 = t_b2  + l * 64;
      const float* g1  = t_g1  + l * 64;
      const float* be1 = t_be1 + l * 64;
      const float* g2  = t_g2  + l * 64;
      const float* be2 = t_be2 + l * 64;

      // layer-top weight prefetch (A-phase + VT)
      bf16x8 fq[2][2], fk[2][2], fvr[2];
#pragma unroll
      for (int fi = 0; fi < 2; ++fi)
#pragma unroll
        for (int kh = 0; kh < 2; ++kh) {
          fq[fi][kh] = wfrag<1>(nullptr, wsW, l6 + 0, fA + fi * 2, kh, lane);
          fk[fi][kh] = wfrag<1>(nullptr, wsW, l6 + 1, fA + fi * 2, kh, lane);
        }
      if (wv >= 4) {
#pragma unroll
        for (int kh = 0; kh < 2; ++kh)
          fvr[kh] = wfrag<1>(nullptr, wsW, l6 + 2, rs, kh, lane);
      }

      // ---- A: Q,K from Y0 (all waves); layer 0 also stages x rows (latency hidden) ----
      {
        if (l == 0) {
          const u16* xr = wsX + ((size_t)b * 96 + s) * 256;
          for (int i = tid; i < 256; i += TPB) {
            u16 v = xr[i];
            int f = i >> 6, n = i & 63;
            xgB[f * 72 + n] = v;
            zTB[n * 232 + f] = v;
          }
        }
        bf16x8 a0 = fragL(Y0, rs * 16, 72, 0, lane);
        bf16x8 a1 = fragL(Y0, rs * 16, 72, 32, lane);
        PRIO1;
#pragma unroll
        for (int fi = 0; fi < 2; ++fi) {
          int f = fA + fi * 2;
          int col = f * 16 + lx;
          {
            f32x4 acc = {0.f, 0.f, 0.f, 0.f};
            acc = MFMA(a0, fq[fi][0], acc);
            acc = MFMA(a1, fq[fi][1], acc);
            float bv = inb[col];
            u16 o4[4]; cvt4u(acc[0] + bv, acc[1] + bv, acc[2] + bv, acc[3] + bv, o4);
#pragma unroll
            for (int j = 0; j < 4; ++j)
              Qb[(rs * 16 + gq + j) * 72 + col] = o4[j];
          }
          {
            f32x4 acc = {0.f, 0.f, 0.f, 0.f};
            acc = MFMA(a0, fk[fi][0], acc);
            acc = MFMA(a1, fk[fi][1], acc);
            float bv = inb[64 + col];
            u16 o4[4]; cvt4u(acc[0] + bv, acc[1] + bv, acc[2] + bv, acc[3] + bv, o4);
#pragma unroll
            for (int j = 0; j < 4; ++j)
              Kb[(rs * 16 + gq + j) * 72 + col] = o4[j];
          }
        }
        PRIO0;
      }
      __syncthreads();

      // ---- B: wv<4 scores+softmax -> Pb (full stripe) ; wv>=4 V^T -> VTb ----
      if (wv < 4) {
        bf16x8 qa0 = fragL(Qb, rs * 16, 72, 0, lane);
        bf16x8 qa1 = fragL(Qb, rs * 16, 72, 32, lane);
        f32x4 sc[4];
        PRIO1;
#pragma unroll
        for (int f = 0; f < 4; ++f) {
          f32x4 acc = {0.f, 0.f, 0.f, 0.f};
          acc = MFMA(qa0, fragL(Kb, f * 16, 72, 0, lane), acc);
          acc = MFMA(qa1, fragL(Kb, f * 16, 72, 32, lane), acc);
#pragma unroll
          for (int j = 0; j < 4; ++j) acc[j] *= 0.125f;
          sc[f] = acc;
        }
        PRIO0;
#pragma unroll
        for (int j = 0; j < 4; ++j) {
          float m1 = fmaxf(fmaxf(sc[0][j], sc[1][j]), fmaxf(sc[2][j], sc[3][j]));
          m1 = fmaxf(m1, __shfl_xor(m1, 1));
          m1 = fmaxf(m1, __shfl_xor(m1, 2));
          m1 = fmaxf(m1, __shfl_xor(m1, 4));
          m1 = fmaxf(m1, __shfl_xor(m1, 8));
          float s1 = 0.f;
#pragma unroll
          for (int f = 0; f < 4; ++f) { float e = __expf(sc[f][j] - m1); sc[f][j] = e; s1 += e; }
          s1 += __shfl_xor(s1, 1); s1 += __shfl_xor(s1, 2);
          s1 += __shfl_xor(s1, 4); s1 += __shfl_xor(s1, 8);
          float inv = 1.f / s1;
          int row = rs * 16 + gq + j;
          u16 o4[4];
          cvt4u(sc[0][j] * inv, sc[1][j] * inv, sc[2][j] * inv, sc[3][j] * inv, o4);
#pragma unroll
          for (int f = 0; f < 4; ++f)
            Pb[row * 72 + f * 16 + lx] = o4[f];
        }
      } else {
#pragma unroll
        for (int f = 0; f < 4; ++f) {
          f32x4 acc = {0.f, 0.f, 0.f, 0.f};
          acc = MFMA(fvr[0], fragL(Y0, f * 16, 72, 0, lane), acc);
          acc = MFMA(fvr[1], fragL(Y0, f * 16, 72, 32, lane), acc);
          int dd0 = rs * 16 + gq;
          u16 o4[4];
          cvt4u(acc[0] + inb[128 + dd0], acc[1] + inb[128 + dd0 + 1],
                acc[2] + inb[128 + dd0 + 2], acc[3] + inb[128 + dd0 + 3], o4);
#pragma unroll
          for (int j = 0; j < 4; ++j)
            VTb[(dd0 + j) * 72 + f * 16 + lx] = o4[j];
        }
      }
      __syncthreads();

      // ---- fused CDEF (l==0) / CDE (l==1): waves 0-3 own stripe rs end-to-end ----
      if (wv < 4) {
        bf16x8 fo[4][2], fw1[4][2];
#pragma unroll
        for (int f = 0; f < 4; ++f)
#pragma unroll
          for (int kh = 0; kh < 2; ++kh) {
            fo[f][kh]  = wfrag<1>(nullptr, wsW, l6 + 3, f, kh, lane);
            fw1[f][kh] = wfrag<1>(nullptr, wsW, l6 + 4, f, kh, lane);
          }
        // C: AO = P @ V (full stripe, 4 tiles)
        {
          bf16x8 pa0 = fragL(Pb, rs * 16, 72, 0, lane);
          bf16x8 pa1 = fragL(Pb, rs * 16, 72, 32, lane);
          PRIO1;
#pragma unroll
          for (int f = 0; f < 4; ++f) {
            f32x4 acc = {0.f, 0.f, 0.f, 0.f};
            acc = MFMA(pa0, fragL(VTb, f * 16, 72, 0, lane), acc);
            acc = MFMA(pa1, fragL(VTb, f * 16, 72, 32, lane), acc);
            u16 o4[4]; cvt4u(acc[0], acc[1], acc[2], acc[3], o4);
#pragma unroll
            for (int j = 0; j < 4; ++j)
              Qb[(rs * 16 + gq + j) * 72 + f * 16 + lx] = o4[j];
          }
          PRIO0;
        }
        // D: proj + residual(Y0) + LN -> Y1 (same-wave LDS RAW, no barrier)
        {
          bf16x8 a0 = fragL(Qb, rs * 16, 72, 0, lane);
          bf16x8 a1 = fragL(Qb, rs * 16, 72, 32, lane);
          float t4[4][4];
          PRIO1;
#pragma unroll
          for (int f = 0; f < 4; ++f) {
            f32x4 acc = {0.f, 0.f, 0.f, 0.f};
            acc = MFMA(a0, fo[f][0], acc);
            acc = MFMA(a1, fo[f][1], acc);
            int col = f * 16 + lx;
            float bv = ob[col];
#pragma unroll
            for (int j = 0; j < 4; ++j) {
              int row = rs * 16 + gq + j;
              t4[f][j] = acc[j] + bv + bf2f(Y0[row * 72 + col]);
            }
          }
          PRIO0;
#pragma unroll
          for (int j = 0; j < 4; ++j) {
            float s1 = t4[0][j] + t4[1][j] + t4[2][j] + t4[3][j];
            float s2 = t4[0][j] * t4[0][j] + t4[1][j] * t4[1][j]
                     + t4[2][j] * t4[2][j] + t4[3][j] * t4[3][j];
            s1 += __shfl_xor(s1, 1); s2 += __shfl_xor(s2, 1);
            s1 += __shfl_xor(s1, 2); s2 += __shfl_xor(s2, 2);
            s1 += __shfl_xor(s1, 4); s2 += __shfl_xor(s2, 4);
            s1 += __shfl_xor(s1, 8); s2 += __shfl_xor(s2, 8);
            float mu = s1 * 0.015625f;
            float rstd = rsqrtf(s2 * 0.015625f - mu * mu + 1e-5f);
            int row = rs * 16 + gq + j;
            u16 o4[4];
            cvt4u((t4[0][j] - mu) * rstd * g1[0 * 16 + lx] + be1[0 * 16 + lx],
                  (t4[1][j] - mu) * rstd * g1[1 * 16 + lx] + be1[1 * 16 + lx],
                  (t4[2][j] - mu) * rstd * g1[2 * 16 + lx] + be1[2 * 16 + lx],
                  (t4[3][j] - mu) * rstd * g1[3 * 16 + lx] + be1[3 * 16 + lx], o4);
#pragma unroll
            for (int f = 0; f < 4; ++f)
              Y1[row * 72 + f * 16 + lx] = o4[f];
          }
        }
        // E: FF1 relu -> Kb (full stripe)
        {
          bf16x8 a0 = fragL(Y1, rs * 16, 72, 0, lane);
          bf16x8 a1 = fragL(Y1, rs * 16, 72, 32, lane);
          PRIO1;
#pragma unroll
          for (int f = 0; f < 4; ++f) {
            f32x4 acc = {0.f, 0.f, 0.f, 0.f};
            acc = MFMA(a0, fw1[f][0], acc);
            acc = MFMA(a1, fw1[f][1], acc);
            int col = f * 16 + lx;
            float bv = bb1[col];
            u16 o4[4];
            cvt4u(fmaxf(acc[0] + bv, 0.f), fmaxf(acc[1] + bv, 0.f),
                  fmaxf(acc[2] + bv, 0.f), fmaxf(acc[3] + bv, 0.f), o4);
#pragma unroll
            for (int j = 0; j < 4; ++j)
              Kb[(rs * 16 + gq + j) * 72 + col] = o4[j];
          }
          PRIO0;
        }
        // F (layer 1 only): FF2 + residual(Y1) + LN -> Y0
        if (l == 0) {
          bf16x8 fw2[4][2];
#pragma unroll
          for (int f = 0; f < 4; ++f)
#pragma unroll
            for (int kh = 0; kh < 2; ++kh)
              fw2[f][kh] = wfrag<1>(nullptr, wsW, l6 + 5, f, kh, lane);
          bf16x8 a0 = fragL(Kb, rs * 16, 72, 0, lane);
          bf16x8 a1 = fragL(Kb, rs * 16, 72, 32, lane);
          float t4[4][4];
          PRIO1;
#pragma unroll
          for (int f = 0; f < 4; ++f) {
            f32x4 acc = {0.f, 0.f, 0.f, 0.f};
            acc = MFMA(a0, fw2[f][0], acc);
            acc = MFMA(a1, fw2[f][1], acc);
            int col = f * 16 + lx;
            float bv = bb2[col];
#pragma unroll
            for (int j = 0; j < 4; ++j) {
              int row = rs * 16 + gq + j;
              t4[f][j] = acc[j] + bv + bf2f(Y1[row * 72 + col]);
            }
          }
          PRIO0;
#pragma unroll
          for (int j = 0; j < 4; ++j) {
            float s1 = t4[0][j] + t4[1][j] + t4[2][j] + t4[3][j];
            float s2 = t4[0][j] * t4[0][j] + t4[1][j] * t4[1][j]
                     + t4[2][j] * t4[2][j] + t4[3][j] * t4[3][j];
            s1 += __shfl_xor(s1, 1); s2 += __shfl_xor(s2, 1);
            s1 += __shfl_xor(s1, 2); s2 += __shfl_xor(s2, 2);
            s1 += __shfl_xor(s1, 4); s2 += __shfl_xor(s2, 4);
            s1 += __shfl_xor(s1, 8); s2 += __shfl_xor(s2, 8);
            float mu = s1 * 0.015625f;
            float rstd = rsqrtf(s2 * 0.015625f - mu * mu + 1e-5f);
            int row = rs * 16 + gq + j;
            u16 o4[4];
            cvt4u((t4[0][j] - mu) * rstd * g2[0 * 16 + lx] + be2[0 * 16 + lx],
                  (t4[1][j] - mu) * rstd * g2[1 * 16 + lx] + be2[1 * 16 + lx],
                  (t4[2][j] - mu) * rstd * g2[2 * 16 + lx] + be2[2 * 16 + lx],
                  (t4[3][j] - mu) * rstd * g2[3 * 16 + lx] + be2[3 * 16 + lx], o4);
#pragma unroll
            for (int f = 0; f < 4; ++f)
              Y0[row * 72 + f * 16 + lx] = o4[f];
          }
        }
      }
      __syncthreads();

      // ---- F2 (layer 2): ALL waves duplicated LN, keep y in regs; fused hd epilogue ----
      if (l == 1) {
        bf16x8 fw2[4][2];
#pragma unroll
        for (int f = 0; f < 4; ++f)
#pragma unroll
          for (int kh = 0; kh < 2; ++kh)
            fw2[f][kh] = wfrag<1>(nullptr, wsW, l6 + 5, f, kh, lane);
        bf16x8 a0 = fragL(Kb, rs * 16, 72, 0, lane);
        bf16x8 a1 = fragL(Kb, rs * 16, 72, 32, lane);
        float t4[4][4];
        PRIO1;
#pragma unroll
        for (int f = 0; f < 4; ++f) {
          f32x4 acc = {0.f, 0.f, 0.f, 0.f};
          acc = MFMA(a0, fw2[f][0], acc);
          acc = MFMA(a1, fw2[f][1], acc);
          int col = f * 16 + lx;
          float bv = bb2[col];
#pragma unroll
          for (int j = 0; j < 4; ++j) {
            int row = rs * 16 + gq + j;
            t4[f][j] = acc[j] + bv + bf2f(Y1[row * 72 + col]);
          }
        }
        PRIO0;
#pragma unroll
        for (int j = 0; j < 4; ++j) {
          float s1 = t4[0][j] + t4[1][j] + t4[2][j] + t4[3][j];
          float s2 = t4[0][j] * t4[0][j] + t4[1][j] * t4[1][j]
                   + t4[2][j] * t4[2][j] + t4[3][j] * t4[3][j];
          s1 += __shfl_xor(s1, 1); s2 += __shfl_xor(s2, 1);
          s1 += __shfl_xor(s1, 2); s2 += __shfl_xor(s2, 2);
          s1 += __shfl_xor(s1, 4); s2 += __shfl_xor(s2, 4);
          s1 += __shfl_xor(s1, 8); s2 += __shfl_xor(s2, 8);
          float mu = s1 * 0.015625f;
          float rstd = rsqrtf(s2 * 0.015625f - mu * mu + 1e-5f);
#pragma unroll
          for (int f = 0; f < 4; ++f) {
            int col = f * 16 + lx;
            t4[f][j] = (t4[f][j] - mu) * rstd * g2[col] + be2[col];  // normalized y
          }
        }
        // hd from registers (lane-local, owned o-cols)
        const int nb = rs * 16 + gq;
#pragma unroll
        for (int f = 0; f < 4; ++f) {
          if ((f >> 1) == (wv >> 2)) {
            const int ff = f & 1;
            int o = f * 16 + lx;
            float hd0 = sq1 * hreg[ff][0] - sq2 * t4[f][0];
            float hd1 = sq1 * hreg[ff][1] - sq2 * t4[f][1];
            float hd2 = sq1 * hreg[ff][2] - sq2 * t4[f][2];
            float hd3 = sq1 * hreg[ff][3] - sq2 * t4[f][3];
            hdreg[ff][0] = hd0; hdreg[ff][1] = hd1;
            hdreg[ff][2] = hd2; hdreg[ff][3] = hd3;
            unsigned p0 = cvt2(hd0, hd1), p1 = cvt2(hd2, hd3);
            zTB[(nb + 0) * 232 + 4 + o] = (u16)p0;
            zTB[(nb + 1) * 232 + 4 + o] = (u16)(p0 >> 16);
            zTB[(nb + 2) * 232 + 4 + o] = (u16)p1;
            zTB[(nb + 3) * 232 + 4 + o] = (u16)(p1 >> 16);
            uint2 pk; pk.x = p0; pk.y = p1;
            *(uint2*)(xgB + (4 + o) * 72 + nb) = pk;
          }
        }
        __syncthreads();
      }
    }

    // ---- fused HJ: each wave computes BOTH adj and adj2 tiles for its stripe (dup),
    //      then conv+gate reads only self-written / barrier-covered zT. One barrier total.
    {
      f32x4 aU0 = {0.f,0.f,0.f,0.f}, aU1 = {0.f,0.f,0.f,0.f};
      f32x4 aC0 = {0.f,0.f,0.f,0.f}, aC1 = {0.f,0.f,0.f,0.f};
      bf16x8 g0 = *(const bf16x8*)(wsA2 + rs * 1024 + lane * 8);
      bf16x8 g1 = *(const bf16x8*)(wsA2 + rs * 1024 + 512 + lane * 8);
      bf16x8 aj0 = fragL(adjB, rs * 16, 72, 0, lane);
      bf16x8 aj1 = fragL(adjB, rs * 16, 72, 32, lane);

#define HT(A0, A1, CF, OFF) { \
      f32x4 acc = {0.f,0.f,0.f,0.f}; \
      acc = MFMA(A0, fragL(xgB, (CF) * 16, 72, 0, lane), acc); \
      acc = MFMA(A1, fragL(xgB, (CF) * 16, 72, 32, lane), acc); \
      int c = (CF) * 16 + lx; \
      if (c < 68) { u16 o4[4]; cvt4u(acc[0], acc[1], acc[2], acc[3], o4); \
        _Pragma("unroll") for (int j = 0; j < 4; ++j) \
          zTB[(rs * 16 + gq + j) * 232 + (OFF) + c] = o4[j]; } }

      PRIO1;
      // x1T: all 5 col-frags of own stripe
      HT(aj0, aj1, 0, 68); HT(aj0, aj1, 1, 68); HT(aj0, aj1, 2, 68);
      HT(aj0, aj1, 3, 68); HT(aj0, aj1, 4, 68);
      // J partial on kh 0..1 (zT cols 0..63 ready since F2 barrier)
#pragma unroll
      for (int kh = 0; kh < 2; ++kh) {
        bf16x8 a = fragL(zTB, rs * 16, 232, kh * 32, lane);
        {
          const u16* pu = uwcwB + (size_t)((of0 + 0) * 7 + kh) * 512 + lane * 8;
          const u16* pc = uwcwB + (size_t)((4 + of0 + 0) * 7 + kh) * 512 + lane * 8;
          aU0 = MFMA(a, *(const bf16x8*)pu, aU0);
          aC0 = MFMA(a, *(const bf16x8*)pc, aC0);
        }
        {
          const u16* pu = uwcwB + (size_t)((of0 + 1) * 7 + kh) * 512 + lane * 8;
          const u16* pc = uwcwB + (size_t)((4 + of0 + 1) * 7 + kh) * 512 + lane * 8;
          aU1 = MFMA(a, *(const bf16x8*)pu, aU1);
          aC1 = MFMA(a, *(const bf16x8*)pc, aC1);
        }
      }
      // x2T: all 5 col-frags of own stripe
      HT(g0, g1, 0, 136); HT(g0, g1, 1, 136); HT(g0, g1, 2, 136);
      HT(g0, g1, 3, 136); HT(g0, g1, 4, 136);
#undef HT

      // J: conv kh 2..6 (reads own-stripe zT; own writes ordered by lgkmcnt)
#pragma unroll
      for (int kh = 2; kh < 7; ++kh) {
        bf16x8 a = fragL(zTB, rs * 16, 232, kh * 32, lane);
        {
          const u16* pu = uwcwB + (size_t)((of0 + 0) * 7 + kh) * 512 + lane * 8;
          const u16* pc = uwcwB + (size_t)((4 + of0 + 0) * 7 + kh) * 512 + lane * 8;
          aU0 = MFMA(a, *(const bf16x8*)pu, aU0);
          aC0 = MFMA(a, *(const bf16x8*)pc, aC0);
        }
        {
          const u16* pu = uwcwB + (size_t)((of0 + 1) * 7 + kh) * 512 + lane * 8;
          const u16* pc = uwcwB + (size_t)((4 + of0 + 1) * 7 + kh) * 512 + lane * 8;
          aU1 = MFMA(a, *(const bf16x8*)pu, aU1);
          aC1 = MFMA(a, *(const bf16x8*)pc, aC1);
        }
      }
      PRIO0;
      const int nb = rs * 16 + gq;
#pragma unroll
      for (int ff = 0; ff < 2; ++ff) {
        f32x4 aU = ff ? aU1 : aU0;
        f32x4 aC = ff ? aC1 : aC0;
        float bu_ = ff ? buo2 : buo;
        float bc_ = ff ? bco2 : bco;
        int o = (of0 + ff) * 16 + lx;
        float4 ov;
#pragma unroll
        for (int j = 0; j < 4; ++j) {
          float u = 1.f / (1.f + __expf(-(aU[j] + bu_)));
          float z = aC[j] + bc_;
          z = fminf(fmaxf(z, -15.f), 15.f);
          float e2 = __expf(2.f * z);
          float cval = (e2 - 1.f) / (e2 + 1.f);
          float hn = u * hdreg[ff][j] + (1.f - u) * cval;
          hreg[ff][j] = hn;
          (&ov.x)[j] = hn;
        }
        unsigned pk0 = cvt2(ov.x, ov.y), pk1 = cvt2(ov.z, ov.w);
        Y0[(nb + 0) * 72 + o] = (u16)pk0;
        Y0[(nb + 1) * 72 + o] = (u16)(pk0 >> 16);
        Y0[(nb + 2) * 72 + o] = (u16)pk1;
        Y0[(nb + 3) * 72 + o] = (u16)(pk1 >> 16);
        *(float4*)(wsOut + ((size_t)b * 96 + s) * 4096 + o * 64 + nb) = ov;
      }
    }
    __syncthreads();
  }
}

// ================== FALLBACK (no workspace; R7-proven path, direct out) ==================
__global__ __launch_bounds__(TPB, 2)
void gcrnn_fb(const float* __restrict__ x, const float* __restrict__ adj,
              const float* __restrict__ h0,
              const float* __restrict__ t_inw, const float* __restrict__ t_inb,
              const float* __restrict__ t_ow,  const float* __restrict__ t_ob,
              const float* __restrict__ t_w1,  const float* __restrict__ t_b1,
              const float* __restrict__ t_w2,  const float* __restrict__ t_b2,
              const float* __restrict__ t_g1,  const float* __restrict__ t_be1,
              const float* __restrict__ t_g2,  const float* __restrict__ t_be2,
              const float* __restrict__ uw,    const float* __restrict__ ub,
              const float* __restrict__ cw,    const float* __restrict__ cb,
              float* __restrict__ out)
{
  const int b = blockIdx.x;
  const int tid = threadIdx.x;
  const int wv = tid >> 6;
  const int lane = tid & 63;
  const int lx = lane & 15;
  const int gq = (lane >> 4) << 2;
  const int rs = wv & 3;
  const int of0 = (wv >> 2) * 2;
  const int fA = wv >> 2;

  __shared__ __align__(16) u16 adjB[64 * 72];
  __shared__ __align__(16) u16 adj2B[64 * 72];
  __shared__ __align__(16) u16 ysB[64 * 72];
  __shared__ __align__(16) u16 pool[4 * 4608];
  __shared__ __align__(16) u16 zTB[64 * 232];
  __shared__ __align__(16) u16 uwcwB[2 * 4 * 7 * 512];

  u16* Qb  = pool;
  u16* Kb  = pool + 4608;
  u16* VTb = pool + 9216;
  u16* Pb  = pool + 13824;
  u16* xgB = pool;

  float hreg[2][4];
  {
    const int nb = rs * 16 + gq;
#pragma unroll
    for (int ff = 0; ff < 2; ++ff) {
      int o = (of0 + ff) * 16 + lx;
      float4 hv = *(const float4*)(h0 + (size_t)b * 4096 + o * 64 + nb);
#pragma unroll
      for (int j = 0; j < 4; ++j) {
        hreg[ff][j] = (&hv.x)[j];
        ysB[(nb + j) * 72 + o] = f2bf(hreg[ff][j]);
      }
    }
  }
  for (int i = tid; i < 4096; i += TPB)
    adjB[(i >> 6) * 72 + (i & 63)] = f2bf(adj[i]);
  for (int i = tid; i < 4096; i += TPB) {
    int w = i >> 6, u = i & 63;
    float sum = 0.f;
    for (int v = 0; v < 64; ++v) sum += adj[w * 64 + v] * adj[v * 64 + u];
    adj2B[w * 72 + u] = f2bf(sum);
  }
  for (int i = tid; i < 2 * 4 * 7 * 512; i += TPB) {
    int t = i;
    int j = t & 7; t >>= 3;
    int ln = t & 63; t >>= 6;
    int kh = t % 7; t /= 7;
    int f = t & 3; int mat = t >> 2;
    int o = f * 16 + (ln & 15);
    int k = kh * 32 + ((ln >> 4) << 3) + j;
    const float* W = mat ? cw : uw;
    uwcwB[i] = (k < 204) ? f2bf(W[o * 204 + k]) : (u16)0;
  }
  for (int i = tid; i < 64 * 28; i += TPB)
    zTB[(i / 28) * 232 + 204 + (i % 28)] = 0;
  __syncthreads();

  const float* times = x + ((size_t)b * 3 + 2) * 64 * 96;
  float hdreg[2][4];

  for (int s = 0; s < 96; ++s) {
    float dcur = (s == 0) ? 0.f : (times[s] - times[s - 1]);
    float sq1 = sqrtf(1.f - dcur), sq2 = sqrtf(dcur);

    for (int l = 0; l < 2; ++l) {
      const float* inw = t_inw + l * 12288;
      const float* inb = t_inb + l * 192;
      const float* ow  = t_ow  + l * 4096;
      const float* ob  = t_ob  + l * 64;
      const float* w1  = t_w1  + l * 4096;
      const float* bb1 = t_b1  + l * 64;
      const float* w2  = t_w2  + l * 4096;
      const float* bb2 = t_b2  + l * 64;
      const float* g1  = t_g1  + l * 64;
      const float* be1 = t_be1 + l * 64;
      const float* g2  = t_g2  + l * 64;
      const float* be2 = t_be2 + l * 64;

      {
        bf16x8 a0 = fragL(ysB, rs * 16, 72, 0, lane);
        bf16x8 a1 = fragL(ysB, rs * 16, 72, 32, lane);
#pragma unroll
        for (int fi = 0; fi < 2; ++fi) {
          int f = fA + fi * 2;
          int col = f * 16 + lx;
          {
            f32x4 acc = {0.f, 0.f, 0.f, 0.f};
            acc = MFMA(a0, fragG(inw, f * 16, 64, 0, lane), acc);
            acc = MFMA(a1, fragG(inw, f * 16, 64, 32, lane), acc);
            float bv = inb[col];
            u16 o4[4]; cvt4u(acc[0] + bv, acc[1] + bv, acc[2] + bv, acc[3] + bv, o4);
#pragma unroll
            for (int j = 0; j < 4; ++j)
              Qb[(rs * 16 + gq + j) * 72 + col] = o4[j];
          }
          {
            f32x4 acc = {0.f, 0.f, 0.f, 0.f};
            acc = MFMA(a0, fragG(inw + 4096, f * 16, 64, 0, lane), acc);
            acc = MFMA(a1, fragG(inw + 4096, f * 16, 64, 32, lane), acc);
            float bv = inb[64 + col];
            u16 o4[4]; cvt4u(acc[0] + bv, acc[1] + bv, acc[2] + bv, acc[3] + bv, o4);
#pragma unroll
            for (int j = 0; j < 4; ++j)
              Kb[(rs * 16 + gq + j) * 72 + col] = o4[j];
          }
        }
      }
      __syncthreads();

      if (wv < 4) {
        bf16x8 qa0 = fragL(Qb, rs * 16, 72, 0, lane);
        bf16x8 qa1 = fragL(Qb, rs * 16, 72, 32, lane);
        f32x4 sc[4];
#pragma unroll
        for (int f = 0; f < 4; ++f) {
          f32x4 acc = {0.f, 0.f, 0.f, 0.f};
          acc = MFMA(qa0, fragL(Kb, f * 16, 72, 0, lane), acc);
          acc = MFMA(qa1, fragL(Kb, f * 16, 72, 32, lane), acc);
#pragma unroll
          for (int j = 0; j < 4; ++j) acc[j] *= 0.125f;
          sc[f] = acc;
        }
#pragma unroll
        for (int j = 0; j < 4; ++j) {
          float m1 = fmaxf(fmaxf(sc[0][j], sc[1][j]), fmaxf(sc[2][j], sc[3][j]));
          m1 = fmaxf(m1, __shfl_xor(m1, 1));
          m1 = fmaxf(m1, __shfl_xor(m1, 2));
          m1 = fmaxf(m1, __shfl_xor(m1, 4));
          m1 = fmaxf(m1, __shfl_xor(m1, 8));
          float s1 = 0.f;
#pragma unroll
          for (int f = 0; f < 4; ++f) { float e = __expf(sc[f][j] - m1); sc[f][j] = e; s1 += e; }
          s1 += __shfl_xor(s1, 1); s1 += __shfl_xor(s1, 2);
          s1 += __shfl_xor(s1, 4); s1 += __shfl_xor(s1, 8);
          float inv = 1.f / s1;
          int row = rs * 16 + gq + j;
          u16 o4[4];
          cvt4u(sc[0][j] * inv, sc[1][j] * inv, sc[2][j] * inv, sc[3][j] * inv, o4);
#pragma unroll
          for (int f = 0; f < 4; ++f)
            Pb[row * 72 + f * 16 + lx] = o4[f];
        }
      } else {
        bf16x8 wa0 = fragG(inw + 8192, rs * 16, 64, 0, lane);
        bf16x8 wa1 = fragG(inw + 8192, rs * 16, 64, 32, lane);
#pragma unroll
        for (int f = 0; f < 4; ++f) {
          f32x4 acc = {0.f, 0.f, 0.f, 0.f};
          acc = MFMA(wa0, fragL(ysB, f * 16, 72, 0, lane), acc);
          acc = MFMA(wa1, fragL(ysB, f * 16, 72, 32, lane), acc);
          int dd0 = rs * 16 + gq;
          u16 o4[4];
          cvt4u(acc[0] + inb[128 + dd0], acc[1] + inb[128 + dd0 + 1],
                acc[2] + inb[128 + dd0 + 2], acc[3] + inb[128 + dd0 + 3], o4);
#pragma unroll
          for (int j = 0; j < 4; ++j)
            VTb[(dd0 + j) * 72 + f * 16 + lx] = o4[j];
        }
      }
      __syncthreads();

      {
        bf16x8 pa0 = fragL(Pb, rs * 16, 72, 0, lane);
        bf16x8 pa1 = fragL(Pb, rs * 16, 72, 32, lane);
#pragma unroll
        for (int fi = 0; fi < 2; ++fi) {
          int f = fA + fi * 2;
          f32x4 acc = {0.f, 0.f, 0.f, 0.f};
          acc = MFMA(pa0, fragL(VTb, f * 16, 72, 0, lane), acc);
          acc = MFMA(pa1, fragL(VTb, f * 16, 72, 32, lane), acc);
          u16 o4[4]; cvt4u(acc[0], acc[1], acc[2], acc[3], o4);
#pragma unroll
          for (int j = 0; j < 4; ++j)
            Qb[(rs * 16 + gq + j) * 72 + f * 16 + lx] = o4[j];
        }
      }
      __syncthreads();

      if (wv < 4) {
        bf16x8 a0 = fragL(Qb, rs * 16, 72, 0, lane);
        bf16x8 a1 = fragL(Qb, rs * 16, 72, 32, lane);
        float t4[4][4];
#pragma unroll
        for (int f = 0; f < 4; ++f) {
          f32x4 acc = {0.f, 0.f, 0.f, 0.f};
          acc = MFMA(a0, fragG(ow, f * 16, 64, 0, lane), acc);
          acc = MFMA(a1, fragG(ow, f * 16, 64, 32, lane), acc);
          int col = f * 16 + lx;
          float bv = ob[col];
#pragma unroll
          for (int j = 0; j < 4; ++j) {
            int row = rs * 16 + gq + j;
            t4[f][j] = acc[j] + bv + bf2f(ysB[row * 72 + col]);
          }
        }
#pragma unroll
        for (int j = 0; j < 4; ++j) {
          float s1 = t4[0][j] + t4[1][j] + t4[2][j] + t4[3][j];
          float s2 = t4[0][j] * t4[0][j] + t4[1][j] * t4[1][j]
                   + t4[2][j] * t4[2][j] + t4[3][j] * t4[3][j];
          s1 += __shfl_xor(s1, 1); s2 += __shfl_xor(s2, 1);
          s1 += __shfl_xor(s1, 2); s2 += __shfl_xor(s2, 2);
          s1 += __shfl_xor(s1, 4); s2 += __shfl_xor(s2, 4);
          s1 += __shfl_xor(s1, 8); s2 += __shfl_xor(s2, 8);
          float mu = s1 * 0.015625f;
          float rstd = rsqrtf(s2 * 0.015625f - mu * mu + 1e-5f);
          int row = rs * 16 + gq + j;
          u16 o4[4];
          cvt4u((t4[0][j] - mu) * rstd * g1[0 * 16 + lx] + be1[0 * 16 + lx],
                (t4[1][j] - mu) * rstd * g1[1 * 16 + lx] + be1[1 * 16 + lx],
                (t4[2][j] - mu) * rstd * g1[2 * 16 + lx] + be1[2 * 16 + lx],
                (t4[3][j] - mu) * rstd * g1[3 * 16 + lx] + be1[3 * 16 + lx], o4);
#pragma unroll
          for (int f = 0; f < 4; ++f)
            ysB[row * 72 + f * 16 + lx] = o4[f];
        }
      }
      __syncthreads();

      {
        bf16x8 a0 = fragL(ysB, rs * 16, 72, 0, lane);
        bf16x8 a1 = fragL(ysB, rs * 16, 72, 32, lane);
#pragma unroll
        for (int fi = 0; fi < 2; ++fi) {
          int f = fA + fi * 2;
          f32x4 acc = {0.f, 0.f, 0.f, 0.f};
          acc = MFMA(a0, fragG(w1, f * 16, 64, 0, lane), acc);
          acc = MFMA(a1, fragG(w1, f * 16, 64, 32, lane), acc);
          int col = f * 16 + lx;
          float bv = bb1[col];
          u16 o4[4];
          cvt4u(fmaxf(acc[0] + bv, 0.f), fmaxf(acc[1] + bv, 0.f),
                fmaxf(acc[2] + bv, 0.f), fmaxf(acc[3] + bv, 0.f), o4);
#pragma unroll
          for (int j = 0; j < 4; ++j)
            Kb[(rs * 16 + gq + j) * 72 + col] = o4[j];
        }
      }
      __syncthreads();

      if (wv < 4) {
        bf16x8 a0 = fragL(Kb, rs * 16, 72, 0, lane);
        bf16x8 a1 = fragL(Kb, rs * 16, 72, 32, lane);
        float t4[4][4];
#pragma unroll
        for (int f = 0; f < 4; ++f) {
          f32x4 acc = {0.f, 0.f, 0.f, 0.f};
          acc = MFMA(a0, fragG(w2, f * 16, 64, 0, lane), acc);
          acc = MFMA(a1, fragG(w2, f * 16, 64, 32, lane), acc);
          int col = f * 16 + lx;
          float bv = bb2[col];
#pragma unroll
          for (int j = 0; j < 4; ++j) {
            int row = rs * 16 + gq + j;
            t4[f][j] = acc[j] + bv + bf2f(ysB[row * 72 + col]);
          }
        }
#pragma unroll
        for (int j = 0; j < 4; ++j) {
          float s1 = t4[0][j] + t4[1][j] + t4[2][j] + t4[3][j];
          float s2 = t4[0][j] * t4[0][j] + t4[1][j] * t4[1][j]
                   + t4[2][j] * t4[2][j] + t4[3][j] * t4[3][j];
          s1 += __shfl_xor(s1, 1); s2 += __shfl_xor(s2, 1);
          s1 += __shfl_xor(s1, 2); s2 += __shfl_xor(s2, 2);
          s1 += __shfl_xor(s1, 4); s2 += __shfl_xor(s2, 4);
          s1 += __shfl_xor(s1, 8); s2 += __shfl_xor(s2, 8);
          float mu = s1 * 0.015625f;
          float rstd = rsqrtf(s2 * 0.015625f - mu * mu + 1e-5f);
          int row = rs * 16 + gq + j;
          u16 o4[4];
          cvt4u((t4[0][j] - mu) * rstd * g2[0 * 16 + lx] + be2[0 * 16 + lx],
                (t4[1][j] - mu) * rstd * g2[1 * 16 + lx] + be2[1 * 16 + lx],
                (t4[2][j] - mu) * rstd * g2[2 * 16 + lx] + be2[2 * 16 + lx],
                (t4[3][j] - mu) * rstd * g2[3 * 16 + lx] + be2[3 * 16 + lx], o4);
#pragma unroll
          for (int f = 0; f < 4; ++f)
            ysB[row * 72 + f * 16 + lx] = o4[f];
        }
      }
      __syncthreads();
    }

    {
      for (int i = tid; i < 256; i += TPB) {
        int f = i >> 6, n = i & 63;
        float v = (f < 3) ? x[(((size_t)b * 3 + f) * 64 + n) * 96 + s] : dcur;
        u16 v16 = f2bf(v);
        xgB[f * 72 + n] = v16;
        zTB[n * 232 + f] = v16;
      }
      const int nb = rs * 16 + gq;
#pragma unroll
      for (int ff = 0; ff < 2; ++ff) {
        int o = (of0 + ff) * 16 + lx;
        float hd0 = sq1 * hreg[ff][0] - sq2 * bf2f(ysB[(nb + 0) * 72 + o]);
        float hd1 = sq1 * hreg[ff][1] - sq2 * bf2f(ysB[(nb + 1) * 72 + o]);
        float hd2 = sq1 * hreg[ff][2] - sq2 * bf2f(ysB[(nb + 2) * 72 + o]);
        float hd3 = sq1 * hreg[ff][3] - sq2 * bf2f(ysB[(nb + 3) * 72 + o]);
        hdreg[ff][0] = hd0; hdreg[ff][1] = hd1; hdreg[ff][2] = hd2; hdreg[ff][3] = hd3;
        unsigned p0 = cvt2(hd0, hd1), p1 = cvt2(hd2, hd3);
        zTB[(nb + 0) * 232 + 4 + o] = (u16)p0;
        zTB[(nb + 1) * 232 + 4 + o] = (u16)(p0 >> 16);
        zTB[(nb + 2) * 232 + 4 + o] = (u16)p1;
        zTB[(nb + 3) * 232 + 4 + o] = (u16)(p1 >> 16);
        uint2 pk; pk.x = p0; pk.y = p1;
        *(uint2*)(xgB + (4 + o) * 72 + nb) = pk;
      }
    }
    __syncthreads();

    for (int t = wv; t < 40; t += 8) {
      int which = (t >= 20) ? 1 : 0;
      int tt = t - which * 20;
      int rw = tt & 3, cf = tt >> 2;
      const u16* A = which ? adj2B : adjB;
      f32x4 acc = {0.f, 0.f, 0.f, 0.f};
      acc = MFMA(fragL(A, rw * 16, 72, 0, lane), fragL(xgB, cf * 16, 72, 0, lane), acc);
      acc = MFMA(fragL(A, rw * 16, 72, 32, lane), fragL(xgB, cf * 16, 72, 32, lane), acc);
      int c = cf * 16 + lx;
      if (c < 68) {
        u16 o4[4]; cvt4u(acc[0], acc[1], acc[2], acc[3], o4);
#pragma unroll
        for (int j = 0; j < 4; ++j)
          zTB[(rw * 16 + gq + j) * 232 + 68 + which * 68 + c] = o4[j];
      }
    }
    __syncthreads();

    {
      f32x4 aU[2] = {{0.f,0.f,0.f,0.f},{0.f,0.f,0.f,0.f}};
      f32x4 aC[2] = {{0.f,0.f,0.f,0.f},{0.f,0.f,0.f,0.f}};
#pragma unroll
      for (int kh = 0; kh < 7; ++kh) {
        bf16x8 a = fragL(zTB, rs * 16, 232, kh * 32, lane);
#pragma unroll
        for (int ff = 0; ff < 2; ++ff) {
          int f = of0 + ff;
          const u16* pu = uwcwB + (size_t)((0 * 4 + f) * 7 + kh) * 512 + lane * 8;
          const u16* pc = uwcwB + (size_t)((1 * 4 + f) * 7 + kh) * 512 + lane * 8;
          aU[ff] = MFMA(a, *(const bf16x8*)pu, aU[ff]);
          aC[ff] = MFMA(a, *(const bf16x8*)pc, aC[ff]);
        }
      }
      const int nb = rs * 16 + gq;
#pragma unroll
      for (int ff = 0; ff < 2; ++ff) {
        int o = (of0 + ff) * 16 + lx;
        float bu_ = ub[o], bc_ = cb[o];
        float4 ov;
#pragma unroll
        for (int j = 0; j < 4; ++j) {
          float u = 1.f / (1.f + __expf(-(aU[ff][j] + bu_)));
          float z = aC[ff][j] + bc_;
          z = fminf(fmaxf(z, -15.f), 15.f);
          float e2 = __expf(2.f * z);
          float cval = (e2 - 1.f) / (e2 + 1.f);
          float hn = u * hdreg[ff][j] + (1.f - u) * cval;
          hreg[ff][j] = hn;
          (&ov.x)[j] = hn;
        }
        unsigned pk0 = cvt2(ov.x, ov.y), pk1 = cvt2(ov.z, ov.w);
        ysB[(nb + 0) * 72 + o] = (u16)pk0;
        ysB[(nb + 1) * 72 + o] = (u16)(pk0 >> 16);
        ysB[(nb + 2) * 72 + o] = (u16)pk1;
        ysB[(nb + 3) * 72 + o] = (u16)(pk1 >> 16);
#pragma unroll
        for (int j = 0; j < 4; ++j)
          out[((size_t)(b * 64 + (nb + j)) * 64 + o) * 96 + s] = (&ov.x)[j];
      }
    }
    __syncthreads();
  }
}

// ws [b][s][d][n] -> out [b][n][d][s]
__global__ __launch_bounds__(256)
void transp_kernel(const float* __restrict__ ws, float* __restrict__ out) {
  int blk = blockIdx.x;
  int b = blk >> 6, o = blk & 63;
  __shared__ float t[96 * 68];
  for (int i = threadIdx.x; i < 96 * 64; i += 256) {
    int ss = i >> 6, n = i & 63;
    t[ss * 68 + n] = ws[((size_t)b * 96 + ss) * 4096 + o * 64 + n];
  }
  __syncthreads();
  for (int i = threadIdx.x; i < 64 * 96; i += 256) {
    int n = i / 96, ss = i - n * 96;
    out[((size_t)(b * 64 + n) * 64 + o) * 96 + ss] = t[ss * 68 + n];
  }
}

extern "C" void kernel_launch(void* const* d_in, const int* in_sizes, int n_in,
                              void* d_out, int out_size, void* d_ws, size_t ws_size,
                              hipStream_t stream)
{
  (void)in_sizes; (void)n_in; (void)out_size;
  const float* x     = (const float*)d_in[0];
  const float* adj   = (const float*)d_in[1];
  const float* h0    = (const float*)d_in[3];
  const float* t_inw = (const float*)d_in[4];
  const float* t_inb = (const float*)d_in[5];
  const float* t_ow  = (const float*)d_in[6];
  const float* t_ob  = (const float*)d_in[7];
  const float* t_w1  = (const float*)d_in[8];
  const float* t_b1  = (const float*)d_in[9];
  const float* t_w2  = (const float*)d_in[10];
  const float* t_b2  = (const float*)d_in[11];
  const float* t_g1  = (const float*)d_in[12];
  const float* t_be1 = (const float*)d_in[13];
  const float* t_g2  = (const float*)d_in[14];
  const float* t_be2 = (const float*)d_in[15];
  const float* uw    = (const float*)d_in[16];
  const float* ub    = (const float*)d_in[17];
  const float* cw    = (const float*)d_in[18];
  const float* cb    = (const float*)d_in[19];
  float* out = (float*)d_out;

  // ws layout: [wsW 98304][wsA2 8192][wsDT 49152][wsX 6291456][stage 201326592]
  const size_t offA2    = 98304;
  const size_t offDT    = 106496;
  const size_t offX     = 155648;
  const size_t offStage = 6447104;
  const size_t stageBytes = (size_t)128 * 96 * 4096 * 4;

  if (ws_size >= offStage + stageBytes) {
    u16*   wsW   = (u16*)d_ws;
    u16*   wsA2  = (u16*)((char*)d_ws + offA2);
    float* wsDT  = (float*)((char*)d_ws + offDT);
    u16*   wsX   = (u16*)((char*)d_ws + offX);
    float* wsOut = (float*)((char*)d_ws + offStage);

    hipLaunchKernelGGL(prep_kernel, dim3(141), dim3(256), 0, stream,
                       t_inw, t_ow, t_w1, t_w2, adj, x, wsW, wsA2, wsDT, wsX);
    hipLaunchKernelGGL(gcrnn_fast, dim3(128), dim3(TPB), 0, stream,
                       adj, h0, t_inb, t_ob, t_b1, t_b2, t_g1, t_be1, t_g2, t_be2,
                       uw, ub, cw, cb, wsW, wsA2, wsDT, wsX, wsOut);
    hipLaunchKernelGGL(transp_kernel, dim3(128 * 64), dim3(256), 0, stream, wsOut, out);
  } else {
    hipLaunchKernelGGL(gcrnn_fb, dim3(128), dim3(TPB), 0, stream,
                       x, adj, h0, t_inw, t_inb, t_ow, t_ob, t_w1, t_b1,
                       t_w2, t_b2, t_g1, t_be1, t_g2, t_be2, uw, ub, cw, cb, out);
  }
}

// Round 13
// 1406.104 us; speedup vs baseline: 1.0934x; 1.0934x over previous
//
#include <hip/hip_runtime.h>
#include <hip/hip_bf16.h>
#include <math.h>

#define TPB 512

typedef __attribute__((ext_vector_type(8))) short bf16x8;
typedef __attribute__((ext_vector_type(4))) float f32x4;
typedef unsigned short u16;

#define MFMA(a, b, c) __builtin_amdgcn_mfma_f32_16x16x32_bf16(a, b, c, 0, 0, 0)

__device__ __forceinline__ u16 f2bf(float f) {   // native HW convert (R10/R11-validated)
  __hip_bfloat16 h = __float2bfloat16(f);
  return *reinterpret_cast<u16*>(&h);
}
__device__ __forceinline__ float bf2f(u16 h) {
  union { unsigned u; float f; } v; v.u = ((unsigned)h) << 16; return v.f;
}
__device__ __forceinline__ unsigned cvt2(float a0, float a1) {
  return (unsigned)f2bf(a0) | ((unsigned)f2bf(a1) << 16);
}
__device__ __forceinline__ void cvt4u(float a0, float a1, float a2, float a3, u16 o[4]) {
  o[0] = f2bf(a0); o[1] = f2bf(a1); o[2] = f2bf(a2); o[3] = f2bf(a3);
}

// fragment from LDS bf16 [row][pitch]: lane row = row0+(lane&15), k = kb+(lane>>4)*8+j
__device__ __forceinline__ bf16x8 fragL(const u16* B, int row0, int pitch, int kb, int lane) {
  return *(const bf16x8*)(B + (row0 + (lane & 15)) * pitch + kb + ((lane >> 4) << 3));
}
// fragment from global fp32 [row][stride] with on-the-fly bf16 convert (fallback)
__device__ __forceinline__ bf16x8 fragG(const float* __restrict__ W, int row0, int stride,
                                        int kb, int lane) {
  const float* p = W + (size_t)(row0 + (lane & 15)) * stride + kb + ((lane >> 4) << 3);
  float4 a = *(const float4*)p, b = *(const float4*)(p + 4);
  bf16x8 r;
  r[0] = (short)f2bf(a.x); r[1] = (short)f2bf(a.y); r[2] = (short)f2bf(a.z); r[3] = (short)f2bf(a.w);
  r[4] = (short)f2bf(b.x); r[5] = (short)f2bf(b.y); r[6] = (short)f2bf(b.z); r[7] = (short)f2bf(b.w);
  return r;
}
template<int PREW>
__device__ __forceinline__ bf16x8 wfrag(const float* __restrict__ Wg,
                                        const u16* __restrict__ Wp,
                                        int m, int f, int kh, int lane) {
  if constexpr (PREW)
    return *(const bf16x8*)(Wp + (size_t)m * 4096 + f * 1024 + kh * 512 + lane * 8);
  else
    return fragG(Wg, f * 16, 64, kh * 32, lane);
}

// prep: 0..11 encoder weights -> frag layout; 12 = adj2 frags; 13..140 = x transpose + dt
__global__ __launch_bounds__(256)
void prep_kernel(const float* __restrict__ t_inw, const float* __restrict__ t_ow,
                 const float* __restrict__ t_w1, const float* __restrict__ t_w2,
                 const float* __restrict__ adj, const float* __restrict__ x,
                 u16* __restrict__ wp, u16* __restrict__ wpA2,
                 float* __restrict__ wsDT, u16* __restrict__ wsX) {
  int m = blockIdx.x;
  if (m == 12) {
    __shared__ float a2[4096];
    for (int e = threadIdx.x; e < 4096; e += 256) {
      int w = e >> 6, u = e & 63;
      float sum = 0.f;
      for (int v = 0; v < 64; ++v) sum += adj[w * 64 + v] * adj[v * 64 + u];
      a2[e] = sum;
    }
    __syncthreads();
    for (int t = threadIdx.x; t < 4096; t += 256) {
      int j = t & 7, ln = (t >> 3) & 63, kh = (t >> 9) & 1, f = t >> 10;
      int row = f * 16 + (ln & 15);
      int k = kh * 32 + ((ln >> 4) << 3) + j;
      wpA2[t] = f2bf(a2[row * 64 + k]);
    }
    return;
  }
  if (m >= 13) {
    int b = m - 13;
    const float* times = x + ((size_t)b * 3 + 2) * 64 * 96;
    for (int i = threadIdx.x; i < 96 * 256; i += 256) {
      int s = i >> 8, idx = i & 255, f = idx >> 6, n = idx & 63;
      float v;
      if (f < 3) v = x[(((size_t)b * 3 + f) * 64 + n) * 96 + s];
      else {
        float dt = s ? (times[s] - times[s - 1]) : 0.f;
        v = dt;
        if (n == 0) wsDT[b * 96 + s] = dt;
      }
      wsX[((size_t)b * 96 + s) * 256 + idx] = f2bf(v);
    }
    return;
  }
  int l = m / 6, r = m % 6;
  const float* W;
  if (r < 3)       W = t_inw + l * 12288 + r * 4096;
  else if (r == 3) W = t_ow + l * 4096;
  else if (r == 4) W = t_w1 + l * 4096;
  else             W = t_w2 + l * 4096;
  for (int t = threadIdx.x; t < 4096; t += 256) {
    int j = t & 7, ln = (t >> 3) & 63, kh = (t >> 9) & 1, f = t >> 10;
    int row = f * 16 + (ln & 15);
    int k = kh * 32 + ((ln >> 4) << 3) + j;
    wp[(size_t)m * 4096 + t] = f2bf(W[row * 64 + k]);
  }
}

// ================== FAST KERNEL: R9 structure (8 barriers/step) + native bf16 cvt ==================
__global__ __launch_bounds__(TPB, 2)
void gcrnn_fast(const float* __restrict__ adj,
                const float* __restrict__ h0,
                const float* __restrict__ t_inb, const float* __restrict__ t_ob,
                const float* __restrict__ t_b1,  const float* __restrict__ t_b2,
                const float* __restrict__ t_g1,  const float* __restrict__ t_be1,
                const float* __restrict__ t_g2,  const float* __restrict__ t_be2,
                const float* __restrict__ uw,    const float* __restrict__ ub,
                const float* __restrict__ cw,    const float* __restrict__ cb,
                const u16* __restrict__ wsW,  const u16* __restrict__ wsA2,
                const float* __restrict__ wsDT, const u16* __restrict__ wsX,
                float* __restrict__ wsOut)
{
  const int b = blockIdx.x;
  const int tid = threadIdx.x;
  const int wv = tid >> 6;          // 0..7
  const int lane = tid & 63;
  const int lx = lane & 15;
  const int gq = (lane >> 4) << 2;  // 0,4,8,12
  const int rs = wv & 3;            // row stripe
  const int of0 = (wv >> 2) * 2;    // owned col-frag pair base {0,2}
  const int fA = wv >> 2;           // Q/K col-frag set {fA, fA+2}

  __shared__ __align__(16) u16 adjB[64 * 72];           //  9216 B
  __shared__ __align__(16) u16 Y0[64 * 72];             //  9216 B (attn input / h^T)
  __shared__ __align__(16) u16 Y1[64 * 72];             //  9216 B (LN1 output)
  __shared__ __align__(16) u16 Qb[64 * 72];             //  9216
  __shared__ __align__(16) u16 Kb[64 * 72];             //  9216
  __shared__ __align__(16) u16 VTb[64 * 72];            //  9216
  __shared__ __align__(16) u16 Pb[64 * 72];             //  9216
  __shared__ __align__(16) u16 xgB[80 * 72];            // 11520 (rows 68..79 zero)
  __shared__ __align__(16) u16 zTB[64 * 232];           // 29696 (cols 204..231 zero)
  __shared__ __align__(16) u16 uwcwB[2 * 4 * 7 * 512];  // 57344
  // total 163072 B

  // ---- one-time init ----
  float hreg[2][4];   // h[o][n]: o=(of0+ff)*16+lx, n=rs*16+gq+j
  {
    const int nb = rs * 16 + gq;
#pragma unroll
    for (int ff = 0; ff < 2; ++ff) {
      int o = (of0 + ff) * 16 + lx;
      float4 hv = *(const float4*)(h0 + (size_t)b * 4096 + o * 64 + nb);
#pragma unroll
      for (int j = 0; j < 4; ++j) {
        hreg[ff][j] = (&hv.x)[j];
        Y0[(nb + j) * 72 + o] = f2bf(hreg[ff][j]);
      }
    }
  }
  for (int i = tid; i < 4096; i += TPB)
    adjB[(i >> 6) * 72 + (i & 63)] = f2bf(adj[i]);
  for (int i = tid; i < 2 * 4 * 7 * 512; i += TPB) {
    int t = i;
    int j = t & 7; t >>= 3;
    int ln = t & 63; t >>= 6;
    int kh = t % 7; t /= 7;
    int f = t & 3; int mat = t >> 2;
    int o = f * 16 + (ln & 15);
    int k = kh * 32 + ((ln >> 4) << 3) + j;
    const float* W = mat ? cw : uw;
    uwcwB[i] = (k < 204) ? f2bf(W[o * 204 + k]) : (u16)0;
  }
  for (int i = tid; i < 64 * 28; i += TPB)
    zTB[(i / 28) * 232 + 204 + (i % 28)] = 0;
  for (int i = tid; i < 12 * 72; i += TPB)
    xgB[68 * 72 + i] = 0;
  __syncthreads();

  const float buo = ub[of0 * 16 + lx], buo2 = ub[(of0 + 1) * 16 + lx];
  const float bco = cb[of0 * 16 + lx], bco2 = cb[(of0 + 1) * 16 + lx];
  float hdreg[2][4];

  for (int s = 0; s < 96; ++s) {
    float dcur = wsDT[b * 96 + s];
    float sq1 = sqrtf(1.f - dcur), sq2 = sqrtf(dcur);

    for (int l = 0; l < 2; ++l) {
      const int l6 = l * 6;
      const float* inb = t_inb + l * 192;
      const float* ob  = t_ob  + l * 64;
      const float* bb1 = t_b1  + l * 64;
      const float* bb2 = t_b2  + l * 64;
      const float* g1  = t_g1  + l * 64;
      const float* be1 = t_be1 + l * 64;
      const float* g2  = t_g2  + l * 64;
      const float* be2 = t_be2 + l * 64;

      // layer-top weight prefetch (A-phase + VT)
      bf16x8 fq[2][2], fk[2][2], fvr[2];
#pragma unroll
      for (int fi = 0; fi < 2; ++fi)
#pragma unroll
        for (int kh = 0; kh < 2; ++kh) {
          fq[fi][kh] = wfrag<1>(nullptr, wsW, l6 + 0, fA + fi * 2, kh, lane);
          fk[fi][kh] = wfrag<1>(nullptr, wsW, l6 + 1, fA + fi * 2, kh, lane);
        }
      if (wv >= 4) {
#pragma unroll
        for (int kh = 0; kh < 2; ++kh)
          fvr[kh] = wfrag<1>(nullptr, wsW, l6 + 2, rs, kh, lane);
      }

      // ---- A: Q,K from Y0 (all waves, 2+2 tiles each) ----
      {
        bf16x8 a0 = fragL(Y0, rs * 16, 72, 0, lane);
        bf16x8 a1 = fragL(Y0, rs * 16, 72, 32, lane);
#pragma unroll
        for (int fi = 0; fi < 2; ++fi) {
          int f = fA + fi * 2;
          int col = f * 16 + lx;
          {
            f32x4 acc = {0.f, 0.f, 0.f, 0.f};
            acc = MFMA(a0, fq[fi][0], acc);
            acc = MFMA(a1, fq[fi][1], acc);
            float bv = inb[col];
            u16 o4[4]; cvt4u(acc[0] + bv, acc[1] + bv, acc[2] + bv, acc[3] + bv, o4);
#pragma unroll
            for (int j = 0; j < 4; ++j)
              Qb[(rs * 16 + gq + j) * 72 + col] = o4[j];
          }
          {
            f32x4 acc = {0.f, 0.f, 0.f, 0.f};
            acc = MFMA(a0, fk[fi][0], acc);
            acc = MFMA(a1, fk[fi][1], acc);
            float bv = inb[64 + col];
            u16 o4[4]; cvt4u(acc[0] + bv, acc[1] + bv, acc[2] + bv, acc[3] + bv, o4);
#pragma unroll
            for (int j = 0; j < 4; ++j)
              Kb[(rs * 16 + gq + j) * 72 + col] = o4[j];
          }
        }
      }
      __syncthreads();

      // ---- B: wv<4 scores+softmax -> Pb (full stripe) ; wv>=4 V^T -> VTb ----
      if (wv < 4) {
        bf16x8 qa0 = fragL(Qb, rs * 16, 72, 0, lane);
        bf16x8 qa1 = fragL(Qb, rs * 16, 72, 32, lane);
        f32x4 sc[4];
#pragma unroll
        for (int f = 0; f < 4; ++f) {
          f32x4 acc = {0.f, 0.f, 0.f, 0.f};
          acc = MFMA(qa0, fragL(Kb, f * 16, 72, 0, lane), acc);
          acc = MFMA(qa1, fragL(Kb, f * 16, 72, 32, lane), acc);
#pragma unroll
          for (int j = 0; j < 4; ++j) acc[j] *= 0.125f;
          sc[f] = acc;
        }
#pragma unroll
        for (int j = 0; j < 4; ++j) {
          float m1 = fmaxf(fmaxf(sc[0][j], sc[1][j]), fmaxf(sc[2][j], sc[3][j]));
          m1 = fmaxf(m1, __shfl_xor(m1, 1));
          m1 = fmaxf(m1, __shfl_xor(m1, 2));
          m1 = fmaxf(m1, __shfl_xor(m1, 4));
          m1 = fmaxf(m1, __shfl_xor(m1, 8));
          float s1 = 0.f;
#pragma unroll
          for (int f = 0; f < 4; ++f) { float e = __expf(sc[f][j] - m1); sc[f][j] = e; s1 += e; }
          s1 += __shfl_xor(s1, 1); s1 += __shfl_xor(s1, 2);
          s1 += __shfl_xor(s1, 4); s1 += __shfl_xor(s1, 8);
          float inv = 1.f / s1;
          int row = rs * 16 + gq + j;
          u16 o4[4];
          cvt4u(sc[0][j] * inv, sc[1][j] * inv, sc[2][j] * inv, sc[3][j] * inv, o4);
#pragma unroll
          for (int f = 0; f < 4; ++f)
            Pb[row * 72 + f * 16 + lx] = o4[f];
        }
      } else {
#pragma unroll
        for (int f = 0; f < 4; ++f) {
          f32x4 acc = {0.f, 0.f, 0.f, 0.f};
          acc = MFMA(fvr[0], fragL(Y0, f * 16, 72, 0, lane), acc);
          acc = MFMA(fvr[1], fragL(Y0, f * 16, 72, 32, lane), acc);
          int dd0 = rs * 16 + gq;
          u16 o4[4];
          cvt4u(acc[0] + inb[128 + dd0], acc[1] + inb[128 + dd0 + 1],
                acc[2] + inb[128 + dd0 + 2], acc[3] + inb[128 + dd0 + 3], o4);
#pragma unroll
          for (int j = 0; j < 4; ++j)
            VTb[(dd0 + j) * 72 + f * 16 + lx] = o4[j];
        }
      }
      __syncthreads();

      // ---- fused CDEF (l==0) / CDE (l==1): waves 0-3 own stripe rs end-to-end ----
      if (wv < 4) {
        bf16x8 fo[4][2], fw1[4][2];
#pragma unroll
        for (int f = 0; f < 4; ++f)
#pragma unroll
          for (int kh = 0; kh < 2; ++kh) {
            fo[f][kh]  = wfrag<1>(nullptr, wsW, l6 + 3, f, kh, lane);
            fw1[f][kh] = wfrag<1>(nullptr, wsW, l6 + 4, f, kh, lane);
          }
        // C: AO = P @ V (full stripe, 4 tiles)
        {
          bf16x8 pa0 = fragL(Pb, rs * 16, 72, 0, lane);
          bf16x8 pa1 = fragL(Pb, rs * 16, 72, 32, lane);
#pragma unroll
          for (int f = 0; f < 4; ++f) {
            f32x4 acc = {0.f, 0.f, 0.f, 0.f};
            acc = MFMA(pa0, fragL(VTb, f * 16, 72, 0, lane), acc);
            acc = MFMA(pa1, fragL(VTb, f * 16, 72, 32, lane), acc);
            u16 o4[4]; cvt4u(acc[0], acc[1], acc[2], acc[3], o4);
#pragma unroll
            for (int j = 0; j < 4; ++j)
              Qb[(rs * 16 + gq + j) * 72 + f * 16 + lx] = o4[j];
          }
        }
        // D: proj + residual(Y0) + LN -> Y1 (same-wave LDS RAW, no barrier)
        {
          bf16x8 a0 = fragL(Qb, rs * 16, 72, 0, lane);
          bf16x8 a1 = fragL(Qb, rs * 16, 72, 32, lane);
          float t4[4][4];
#pragma unroll
          for (int f = 0; f < 4; ++f) {
            f32x4 acc = {0.f, 0.f, 0.f, 0.f};
            acc = MFMA(a0, fo[f][0], acc);
            acc = MFMA(a1, fo[f][1], acc);
            int col = f * 16 + lx;
            float bv = ob[col];
#pragma unroll
            for (int j = 0; j < 4; ++j) {
              int row = rs * 16 + gq + j;
              t4[f][j] = acc[j] + bv + bf2f(Y0[row * 72 + col]);
            }
          }
#pragma unroll
          for (int j = 0; j < 4; ++j) {
            float s1 = t4[0][j] + t4[1][j] + t4[2][j] + t4[3][j];
            float s2 = t4[0][j] * t4[0][j] + t4[1][j] * t4[1][j]
                     + t4[2][j] * t4[2][j] + t4[3][j] * t4[3][j];
            s1 += __shfl_xor(s1, 1); s2 += __shfl_xor(s2, 1);
            s1 += __shfl_xor(s1, 2); s2 += __shfl_xor(s2, 2);
            s1 += __shfl_xor(s1, 4); s2 += __shfl_xor(s2, 4);
            s1 += __shfl_xor(s1, 8); s2 += __shfl_xor(s2, 8);
            float mu = s1 * 0.015625f;
            float rstd = rsqrtf(s2 * 0.015625f - mu * mu + 1e-5f);
            int row = rs * 16 + gq + j;
            u16 o4[4];
            cvt4u((t4[0][j] - mu) * rstd * g1[0 * 16 + lx] + be1[0 * 16 + lx],
                  (t4[1][j] - mu) * rstd * g1[1 * 16 + lx] + be1[1 * 16 + lx],
                  (t4[2][j] - mu) * rstd * g1[2 * 16 + lx] + be1[2 * 16 + lx],
                  (t4[3][j] - mu) * rstd * g1[3 * 16 + lx] + be1[3 * 16 + lx], o4);
#pragma unroll
            for (int f = 0; f < 4; ++f)
              Y1[row * 72 + f * 16 + lx] = o4[f];
          }
        }
        // E: FF1 relu -> Kb (full stripe)
        {
          bf16x8 a0 = fragL(Y1, rs * 16, 72, 0, lane);
          bf16x8 a1 = fragL(Y1, rs * 16, 72, 32, lane);
#pragma unroll
          for (int f = 0; f < 4; ++f) {
            f32x4 acc = {0.f, 0.f, 0.f, 0.f};
            acc = MFMA(a0, fw1[f][0], acc);
            acc = MFMA(a1, fw1[f][1], acc);
            int col = f * 16 + lx;
            float bv = bb1[col];
            u16 o4[4];
            cvt4u(fmaxf(acc[0] + bv, 0.f), fmaxf(acc[1] + bv, 0.f),
                  fmaxf(acc[2] + bv, 0.f), fmaxf(acc[3] + bv, 0.f), o4);
#pragma unroll
            for (int j = 0; j < 4; ++j)
              Kb[(rs * 16 + gq + j) * 72 + col] = o4[j];
          }
        }
        // F (layer 1 only): FF2 + residual(Y1) + LN -> Y0
        if (l == 0) {
          bf16x8 fw2[4][2];
#pragma unroll
          for (int f = 0; f < 4; ++f)
#pragma unroll
            for (int kh = 0; kh < 2; ++kh)
              fw2[f][kh] = wfrag<1>(nullptr, wsW, l6 + 5, f, kh, lane);
          bf16x8 a0 = fragL(Kb, rs * 16, 72, 0, lane);
          bf16x8 a1 = fragL(Kb, rs * 16, 72, 32, lane);
          float t4[4][4];
#pragma unroll
          for (int f = 0; f < 4; ++f) {
            f32x4 acc = {0.f, 0.f, 0.f, 0.f};
            acc = MFMA(a0, fw2[f][0], acc);
            acc = MFMA(a1, fw2[f][1], acc);
            int col = f * 16 + lx;
            float bv = bb2[col];
#pragma unroll
            for (int j = 0; j < 4; ++j) {
              int row = rs * 16 + gq + j;
              t4[f][j] = acc[j] + bv + bf2f(Y1[row * 72 + col]);
            }
          }
#pragma unroll
          for (int j = 0; j < 4; ++j) {
            float s1 = t4[0][j] + t4[1][j] + t4[2][j] + t4[3][j];
            float s2 = t4[0][j] * t4[0][j] + t4[1][j] * t4[1][j]
                     + t4[2][j] * t4[2][j] + t4[3][j] * t4[3][j];
            s1 += __shfl_xor(s1, 1); s2 += __shfl_xor(s2, 1);
            s1 += __shfl_xor(s1, 2); s2 += __shfl_xor(s2, 2);
            s1 += __shfl_xor(s1, 4); s2 += __shfl_xor(s2, 4);
            s1 += __shfl_xor(s1, 8); s2 += __shfl_xor(s2, 8);
            float mu = s1 * 0.015625f;
            float rstd = rsqrtf(s2 * 0.015625f - mu * mu + 1e-5f);
            int row = rs * 16 + gq + j;
            u16 o4[4];
            cvt4u((t4[0][j] - mu) * rstd * g2[0 * 16 + lx] + be2[0 * 16 + lx],
                  (t4[1][j] - mu) * rstd * g2[1 * 16 + lx] + be2[1 * 16 + lx],
                  (t4[2][j] - mu) * rstd * g2[2 * 16 + lx] + be2[2 * 16 + lx],
                  (t4[3][j] - mu) * rstd * g2[3 * 16 + lx] + be2[3 * 16 + lx], o4);
#pragma unroll
            for (int f = 0; f < 4; ++f)
              Y0[row * 72 + f * 16 + lx] = o4[f];
          }
        }
      }
      __syncthreads();

      // ---- F2 (layer 2): ALL waves duplicated LN, keep y in regs; fused hd epilogue ----
      if (l == 1) {
        bf16x8 fw2[4][2];
#pragma unroll
        for (int f = 0; f < 4; ++f)
#pragma unroll
          for (int kh = 0; kh < 2; ++kh)
            fw2[f][kh] = wfrag<1>(nullptr, wsW, l6 + 5, f, kh, lane);
        bf16x8 a0 = fragL(Kb, rs * 16, 72, 0, lane);
        bf16x8 a1 = fragL(Kb, rs * 16, 72, 32, lane);
        float t4[4][4];
#pragma unroll
        for (int f = 0; f < 4; ++f) {
          f32x4 acc = {0.f, 0.f, 0.f, 0.f};
          acc = MFMA(a0, fw2[f][0], acc);
          acc = MFMA(a1, fw2[f][1], acc);
          int col = f * 16 + lx;
          float bv = bb2[col];
#pragma unroll
          for (int j = 0; j < 4; ++j) {
            int row = rs * 16 + gq + j;
            t4[f][j] = acc[j] + bv + bf2f(Y1[row * 72 + col]);
          }
        }
#pragma unroll
        for (int j = 0; j < 4; ++j) {
          float s1 = t4[0][j] + t4[1][j] + t4[2][j] + t4[3][j];
          float s2 = t4[0][j] * t4[0][j] + t4[1][j] * t4[1][j]
                   + t4[2][j] * t4[2][j] + t4[3][j] * t4[3][j];
          s1 += __shfl_xor(s1, 1); s2 += __shfl_xor(s2, 1);
          s1 += __shfl_xor(s1, 2); s2 += __shfl_xor(s2, 2);
          s1 += __shfl_xor(s1, 4); s2 += __shfl_xor(s2, 4);
          s1 += __shfl_xor(s1, 8); s2 += __shfl_xor(s2, 8);
          float mu = s1 * 0.015625f;
          float rstd = rsqrtf(s2 * 0.015625f - mu * mu + 1e-5f);
#pragma unroll
          for (int f = 0; f < 4; ++f) {
            int col = f * 16 + lx;
            t4[f][j] = (t4[f][j] - mu) * rstd * g2[col] + be2[col];  // normalized y
          }
        }
        // x rows + dt into xgB rows 0..3 / zTB cols 0..3
        {
          const u16* xr = wsX + ((size_t)b * 96 + s) * 256;
          for (int i = tid; i < 256; i += TPB) {
            u16 v = xr[i];
            int f = i >> 6, n = i & 63;
            xgB[f * 72 + n] = v;
            zTB[n * 232 + f] = v;
          }
        }
        // hd from registers (lane-local, owned o-cols)
        const int nb = rs * 16 + gq;
#pragma unroll
        for (int f = 0; f < 4; ++f) {
          if ((f >> 1) == (wv >> 2)) {
            const int ff = f & 1;
            int o = f * 16 + lx;
            float hd0 = sq1 * hreg[ff][0] - sq2 * t4[f][0];
            float hd1 = sq1 * hreg[ff][1] - sq2 * t4[f][1];
            float hd2 = sq1 * hreg[ff][2] - sq2 * t4[f][2];
            float hd3 = sq1 * hreg[ff][3] - sq2 * t4[f][3];
            hdreg[ff][0] = hd0; hdreg[ff][1] = hd1;
            hdreg[ff][2] = hd2; hdreg[ff][3] = hd3;
            unsigned p0 = cvt2(hd0, hd1), p1 = cvt2(hd2, hd3);
            zTB[(nb + 0) * 232 + 4 + o] = (u16)p0;
            zTB[(nb + 1) * 232 + 4 + o] = (u16)(p0 >> 16);
            zTB[(nb + 2) * 232 + 4 + o] = (u16)p1;
            zTB[(nb + 3) * 232 + 4 + o] = (u16)(p1 >> 16);
            uint2 pk; pk.x = p0; pk.y = p1;
            *(uint2*)(xgB + (4 + o) * 72 + nb) = pk;
          }
        }
        __syncthreads();
      }
    }

    // ---- fused HJ: each wave computes BOTH adj and adj2 tiles for its stripe (dup),
    //      then conv+gate reads only self-written / barrier-covered zT. One barrier total.
    {
      f32x4 aU0 = {0.f,0.f,0.f,0.f}, aU1 = {0.f,0.f,0.f,0.f};
      f32x4 aC0 = {0.f,0.f,0.f,0.f}, aC1 = {0.f,0.f,0.f,0.f};
      bf16x8 g0 = *(const bf16x8*)(wsA2 + rs * 1024 + lane * 8);
      bf16x8 g1 = *(const bf16x8*)(wsA2 + rs * 1024 + 512 + lane * 8);
      bf16x8 aj0 = fragL(adjB, rs * 16, 72, 0, lane);
      bf16x8 aj1 = fragL(adjB, rs * 16, 72, 32, lane);

#define HT(A0, A1, CF, OFF) { \
      f32x4 acc = {0.f,0.f,0.f,0.f}; \
      acc = MFMA(A0, fragL(xgB, (CF) * 16, 72, 0, lane), acc); \
      acc = MFMA(A1, fragL(xgB, (CF) * 16, 72, 32, lane), acc); \
      int c = (CF) * 16 + lx; \
      if (c < 68) { u16 o4[4]; cvt4u(acc[0], acc[1], acc[2], acc[3], o4); \
        _Pragma("unroll") for (int j = 0; j < 4; ++j) \
          zTB[(rs * 16 + gq + j) * 232 + (OFF) + c] = o4[j]; } }

      // x1T: all 5 col-frags of own stripe
      HT(aj0, aj1, 0, 68); HT(aj0, aj1, 1, 68); HT(aj0, aj1, 2, 68);
      HT(aj0, aj1, 3, 68); HT(aj0, aj1, 4, 68);
      // J partial on kh 0..1 (zT cols 0..63 ready since F2 barrier)
#pragma unroll
      for (int kh = 0; kh < 2; ++kh) {
        bf16x8 a = fragL(zTB, rs * 16, 232, kh * 32, lane);
        {
          const u16* pu = uwcwB + (size_t)((of0 + 0) * 7 + kh) * 512 + lane * 8;
          const u16* pc = uwcwB + (size_t)((4 + of0 + 0) * 7 + kh) * 512 + lane * 8;
          aU0 = MFMA(a, *(const bf16x8*)pu, aU0);
          aC0 = MFMA(a, *(const bf16x8*)pc, aC0);
        }
        {
          const u16* pu = uwcwB + (size_t)((of0 + 1) * 7 + kh) * 512 + lane * 8;
          const u16* pc = uwcwB + (size_t)((4 + of0 + 1) * 7 + kh) * 512 + lane * 8;
          aU1 = MFMA(a, *(const bf16x8*)pu, aU1);
          aC1 = MFMA(a, *(const bf16x8*)pc, aC1);
        }
      }
      // x2T: all 5 col-frags of own stripe
      HT(g0, g1, 0, 136); HT(g0, g1, 1, 136); HT(g0, g1, 2, 136);
      HT(g0, g1, 3, 136); HT(g0, g1, 4, 136);
#undef HT

      // J: conv kh 2..6 (reads own-stripe zT; own writes ordered by lgkmcnt)
#pragma unroll
      for (int kh = 2; kh < 7; ++kh) {
        bf16x8 a = fragL(zTB, rs * 16, 232, kh * 32, lane);
        {
          const u16* pu = uwcwB + (size_t)((of0 + 0) * 7 + kh) * 512 + lane * 8;
          const u16* pc = uwcwB + (size_t)((4 + of0 + 0) * 7 + kh) * 512 + lane * 8;
          aU0 = MFMA(a, *(const bf16x8*)pu, aU0);
          aC0 = MFMA(a, *(const bf16x8*)pc, aC0);
        }
        {
          const u16* pu = uwcwB + (size_t)((of0 + 1) * 7 + kh) * 512 + lane * 8;
          const u16* pc = uwcwB + (size_t)((4 + of0 + 1) * 7 + kh) * 512 + lane * 8;
          aU1 = MFMA(a, *(const bf16x8*)pu, aU1);
          aC1 = MFMA(a, *(const bf16x8*)pc, aC1);
        }
      }
      const int nb = rs * 16 + gq;
#pragma unroll
      for (int ff = 0; ff < 2; ++ff) {
        f32x4 aU = ff ? aU1 : aU0;
        f32x4 aC = ff ? aC1 : aC0;
        float bu_ = ff ? buo2 : buo;
        float bc_ = ff ? bco2 : bco;
        int o = (of0 + ff) * 16 + lx;
        float4 ov;
#pragma unroll
        for (int j = 0; j < 4; ++j) {
          float u = 1.f / (1.f + __expf(-(aU[j] + bu_)));
          float z = aC[j] + bc_;
          z = fminf(fmaxf(z, -15.f), 15.f);
          float e2 = __expf(2.f * z);
          float cval = (e2 - 1.f) / (e2 + 1.f);
          float hn = u * hdreg[ff][j] + (1.f - u) * cval;
          hreg[ff][j] = hn;
          (&ov.x)[j] = hn;
        }
        unsigned pk0 = cvt2(ov.x, ov.y), pk1 = cvt2(ov.z, ov.w);
        Y0[(nb + 0) * 72 + o] = (u16)pk0;
        Y0[(nb + 1) * 72 + o] = (u16)(pk0 >> 16);
        Y0[(nb + 2) * 72 + o] = (u16)pk1;
        Y0[(nb + 3) * 72 + o] = (u16)(pk1 >> 16);
        *(float4*)(wsOut + ((size_t)b * 96 + s) * 4096 + o * 64 + nb) = ov;
      }
    }
    __syncthreads();
  }
}

// ================== FALLBACK (no workspace; R7-proven path, direct out) ==================
__global__ __launch_bounds__(TPB, 2)
void gcrnn_fb(const float* __restrict__ x, const float* __restrict__ adj,
              const float* __restrict__ h0,
              const float* __restrict__ t_inw, const float* __restrict__ t_inb,
              const float* __restrict__ t_ow,  const float* __restrict__ t_ob,
              const float* __restrict__ t_w1,  const float* __restrict__ t_b1,
              const float* __restrict__ t_w2,  const float* __restrict__ t_b2,
              const float* __restrict__ t_g1,  const float* __restrict__ t_be1,
              const float* __restrict__ t_g2,  const float* __restrict__ t_be2,
              const float* __restrict__ uw,    const float* __restrict__ ub,
              const float* __restrict__ cw,    const float* __restrict__ cb,
              float* __restrict__ out)
{
  const int b = blockIdx.x;
  const int tid = threadIdx.x;
  const int wv = tid >> 6;
  const int lane = tid & 63;
  const int lx = lane & 15;
  const int gq = (lane >> 4) << 2;
  const int rs = wv & 3;
  const int of0 = (wv >> 2) * 2;
  const int fA = wv >> 2;

  __shared__ __align__(16) u16 adjB[64 * 72];
  __shared__ __align__(16) u16 adj2B[64 * 72];
  __shared__ __align__(16) u16 ysB[64 * 72];
  __shared__ __align__(16) u16 pool[4 * 4608];
  __shared__ __align__(16) u16 zTB[64 * 232];
  __shared__ __align__(16) u16 uwcwB[2 * 4 * 7 * 512];

  u16* Qb  = pool;
  u16* Kb  = pool + 4608;
  u16* VTb = pool + 9216;
  u16* Pb  = pool + 13824;
  u16* xgB = pool;

  float hreg[2][4];
  {
    const int nb = rs * 16 + gq;
#pragma unroll
    for (int ff = 0; ff < 2; ++ff) {
      int o = (of0 + ff) * 16 + lx;
      float4 hv = *(const float4*)(h0 + (size_t)b * 4096 + o * 64 + nb);
#pragma unroll
      for (int j = 0; j < 4; ++j) {
        hreg[ff][j] = (&hv.x)[j];
        ysB[(nb + j) * 72 + o] = f2bf(hreg[ff][j]);
      }
    }
  }
  for (int i = tid; i < 4096; i += TPB)
    adjB[(i >> 6) * 72 + (i & 63)] = f2bf(adj[i]);
  for (int i = tid; i < 4096; i += TPB) {
    int w = i >> 6, u = i & 63;
    float sum = 0.f;
    for (int v = 0; v < 64; ++v) sum += adj[w * 64 + v] * adj[v * 64 + u];
    adj2B[w * 72 + u] = f2bf(sum);
  }
  for (int i = tid; i < 2 * 4 * 7 * 512; i += TPB) {
    int t = i;
    int j = t & 7; t >>= 3;
    int ln = t & 63; t >>= 6;
    int kh = t % 7; t /= 7;
    int f = t & 3; int mat = t >> 2;
    int o = f * 16 + (ln & 15);
    int k = kh * 32 + ((ln >> 4) << 3) + j;
    const float* W = mat ? cw : uw;
    uwcwB[i] = (k < 204) ? f2bf(W[o * 204 + k]) : (u16)0;
  }
  for (int i = tid; i < 64 * 28; i += TPB)
    zTB[(i / 28) * 232 + 204 + (i % 28)] = 0;
  __syncthreads();

  const float* times = x + ((size_t)b * 3 + 2) * 64 * 96;
  float hdreg[2][4];

  for (int s = 0; s < 96; ++s) {
    float dcur = (s == 0) ? 0.f : (times[s] - times[s - 1]);
    float sq1 = sqrtf(1.f - dcur), sq2 = sqrtf(dcur);

    for (int l = 0; l < 2; ++l) {
      const float* inw = t_inw + l * 12288;
      const float* inb = t_inb + l * 192;
      const float* ow  = t_ow  + l * 4096;
      const float* ob  = t_ob  + l * 64;
      const float* w1  = t_w1  + l * 4096;
      const float* bb1 = t_b1  + l * 64;
      const float* w2  = t_w2  + l * 4096;
      const float* bb2 = t_b2  + l * 64;
      const float* g1  = t_g1  + l * 64;
      const float* be1 = t_be1 + l * 64;
      const float* g2  = t_g2  + l * 64;
      const float* be2 = t_be2 + l * 64;

      {
        bf16x8 a0 = fragL(ysB, rs * 16, 72, 0, lane);
        bf16x8 a1 = fragL(ysB, rs * 16, 72, 32, lane);
#pragma unroll
        for (int fi = 0; fi < 2; ++fi) {
          int f = fA + fi * 2;
          int col = f * 16 + lx;
          {
            f32x4 acc = {0.f, 0.f, 0.f, 0.f};
            acc = MFMA(a0, fragG(inw, f * 16, 64, 0, lane), acc);
            acc = MFMA(a1, fragG(inw, f * 16, 64, 32, lane), acc);
            float bv = inb[col];
            u16 o4[4]; cvt4u(acc[0] + bv, acc[1] + bv, acc[2] + bv, acc[3] + bv, o4);
#pragma unroll
            for (int j = 0; j < 4; ++j)
              Qb[(rs * 16 + gq + j) * 72 + col] = o4[j];
          }
          {
            f32x4 acc = {0.f, 0.f, 0.f, 0.f};
            acc = MFMA(a0, fragG(inw + 4096, f * 16, 64, 0, lane), acc);
            acc = MFMA(a1, fragG(inw + 4096, f * 16, 64, 32, lane), acc);
            float bv = inb[64 + col];
            u16 o4[4]; cvt4u(acc[0] + bv, acc[1] + bv, acc[2] + bv, acc[3] + bv, o4);
#pragma unroll
            for (int j = 0; j < 4; ++j)
              Kb[(rs * 16 + gq + j) * 72 + col] = o4[j];
          }
        }
      }
      __syncthreads();

      if (wv < 4) {
        bf16x8 qa0 = fragL(Qb, rs * 16, 72, 0, lane);
        bf16x8 qa1 = fragL(Qb, rs * 16, 72, 32, lane);
        f32x4 sc[4];
#pragma unroll
        for (int f = 0; f < 4; ++f) {
          f32x4 acc = {0.f, 0.f, 0.f, 0.f};
          acc = MFMA(qa0, fragL(Kb, f * 16, 72, 0, lane), acc);
          acc = MFMA(qa1, fragL(Kb, f * 16, 72, 32, lane), acc);
#pragma unroll
          for (int j = 0; j < 4; ++j) acc[j] *= 0.125f;
          sc[f] = acc;
        }
#pragma unroll
        for (int j = 0; j < 4; ++j) {
          float m1 = fmaxf(fmaxf(sc[0][j], sc[1][j]), fmaxf(sc[2][j], sc[3][j]));
          m1 = fmaxf(m1, __shfl_xor(m1, 1));
          m1 = fmaxf(m1, __shfl_xor(m1, 2));
          m1 = fmaxf(m1, __shfl_xor(m1, 4));
          m1 = fmaxf(m1, __shfl_xor(m1, 8));
          float s1 = 0.f;
#pragma unroll
          for (int f = 0; f < 4; ++f) { float e = __expf(sc[f][j] - m1); sc[f][j] = e; s1 += e; }
          s1 += __shfl_xor(s1, 1); s1 += __shfl_xor(s1, 2);
          s1 += __shfl_xor(s1, 4); s1 += __shfl_xor(s1, 8);
          float inv = 1.f / s1;
          int row = rs * 16 + gq + j;
          u16 o4[4];
          cvt4u(sc[0][j] * inv, sc[1][j] * inv, sc[2][j] * inv, sc[3][j] * inv, o4);
#pragma unroll
          for (int f = 0; f < 4; ++f)
            Pb[row * 72 + f * 16 + lx] = o4[f];
        }
      } else {
        bf16x8 wa0 = fragG(inw + 8192, rs * 16, 64, 0, lane);
        bf16x8 wa1 = fragG(inw + 8192, rs * 16, 64, 32, lane);
#pragma unroll
        for (int f = 0; f < 4; ++f) {
          f32x4 acc = {0.f, 0.f, 0.f, 0.f};
          acc = MFMA(wa0, fragL(ysB, f * 16, 72, 0, lane), acc);
          acc = MFMA(wa1, fragL(ysB, f * 16, 72, 32, lane), acc);
          int dd0 = rs * 16 + gq;
          u16 o4[4];
          cvt4u(acc[0] + inb[128 + dd0], acc[1] + inb[128 + dd0 + 1],
                acc[2] + inb[128 + dd0 + 2], acc[3] + inb[128 + dd0 + 3], o4);
#pragma unroll
          for (int j = 0; j < 4; ++j)
            VTb[(dd0 + j) * 72 + f * 16 + lx] = o4[j];
        }
      }
      __syncthreads();

      {
        bf16x8 pa0 = fragL(Pb, rs * 16, 72, 0, lane);
        bf16x8 pa1 = fragL(Pb, rs * 16, 72, 32, lane);
#pragma unroll
        for (int fi = 0; fi < 2; ++fi) {
          int f = fA + fi * 2;
          f32x4 acc = {0.f, 0.f, 0.f, 0.f};
          acc = MFMA(pa0, fragL(VTb, f * 16, 72, 0, lane), acc);
          acc = MFMA(pa1, fragL(VTb, f * 16, 72, 32, lane), acc);
          u16 o4[4]; cvt4u(acc[0], acc[1], acc[2], acc[3], o4);
#pragma unroll
          for (int j = 0; j < 4; ++j)
            Qb[(rs * 16 + gq + j) * 72 + f * 16 + lx] = o4[j];
        }
      }
      __syncthreads();

      if (wv < 4) {
        bf16x8 a0 = fragL(Qb, rs * 16, 72, 0, lane);
        bf16x8 a1 = fragL(Qb, rs * 16, 72, 32, lane);
        float t4[4][4];
#pragma unroll
        for (int f = 0; f < 4; ++f) {
          f32x4 acc = {0.f, 0.f, 0.f, 0.f};
          acc = MFMA(a0, fragG(ow, f * 16, 64, 0, lane), acc);
          acc = MFMA(a1, fragG(ow, f * 16, 64, 32, lane), acc);
          int col = f * 16 + lx;
          float bv = ob[col];
#pragma unroll
          for (int j = 0; j < 4; ++j) {
            int row = rs * 16 + gq + j;
            t4[f][j] = acc[j] + bv + bf2f(ysB[row * 72 + col]);
          }
        }
#pragma unroll
        for (int j = 0; j < 4; ++j) {
          float s1 = t4[0][j] + t4[1][j] + t4[2][j] + t4[3][j];
          float s2 = t4[0][j] * t4[0][j] + t4[1][j] * t4[1][j]
                   + t4[2][j] * t4[2][j] + t4[3][j] * t4[3][j];
          s1 += __shfl_xor(s1, 1); s2 += __shfl_xor(s2, 1);
          s1 += __shfl_xor(s1, 2); s2 += __shfl_xor(s2, 2);
          s1 += __shfl_xor(s1, 4); s2 += __shfl_xor(s2, 4);
          s1 += __shfl_xor(s1, 8); s2 += __shfl_xor(s2, 8);
          float mu = s1 * 0.015625f;
          float rstd = rsqrtf(s2 * 0.015625f - mu * mu + 1e-5f);
          int row = rs * 16 + gq + j;
          u16 o4[4];
          cvt4u((t4[0][j] - mu) * rstd * g1[0 * 16 + lx] + be1[0 * 16 + lx],
                (t4[1][j] - mu) * rstd * g1[1 * 16 + lx] + be1[1 * 16 + lx],
                (t4[2][j] - mu) * rstd * g1[2 * 16 + lx] + be1[2 * 16 + lx],
                (t4[3][j] - mu) * rstd * g1[3 * 16 + lx] + be1[3 * 16 + lx], o4);
#pragma unroll
          for (int f = 0; f < 4; ++f)
            ysB[row * 72 + f * 16 + lx] = o4[f];
        }
      }
      __syncthreads();

      {
        bf16x8 a0 = fragL(ysB, rs * 16, 72, 0, lane);
        bf16x8 a1 = fragL(ysB, rs * 16, 72, 32, lane);
#pragma unroll
        for (int fi = 0; fi < 2; ++fi) {
          int f = fA + fi * 2;
          f32x4 acc = {0.f, 0.f, 0.f, 0.f};
          acc = MFMA(a0, fragG(w1, f * 16, 64, 0, lane), acc);
          acc = MFMA(a1, fragG(w1, f * 16, 64, 32, lane), acc);
          int col = f * 16 + lx;
          float bv = bb1[col];
          u16 o4[4];
          cvt4u(fmaxf(acc[0] + bv, 0.f), fmaxf(acc[1] + bv, 0.f),
                fmaxf(acc[2] + bv, 0.f), fmaxf(acc[3] + bv, 0.f), o4);
#pragma unroll
          for (int j = 0; j < 4; ++j)
            Kb[(rs * 16 + gq + j) * 72 + col] = o4[j];
        }
      }
      __syncthreads();

      if (wv < 4) {
        bf16x8 a0 = fragL(Kb, rs * 16, 72, 0, lane);
        bf16x8 a1 = fragL(Kb, rs * 16, 72, 32, lane);
        float t4[4][4];
#pragma unroll
        for (int f = 0; f < 4; ++f) {
          f32x4 acc = {0.f, 0.f, 0.f, 0.f};
          acc = MFMA(a0, fragG(w2, f * 16, 64, 0, lane), acc);
          acc = MFMA(a1, fragG(w2, f * 16, 64, 32, lane), acc);
          int col = f * 16 + lx;
          float bv = bb2[col];
#pragma unroll
          for (int j = 0; j < 4; ++j) {
            int row = rs * 16 + gq + j;
            t4[f][j] = acc[j] + bv + bf2f(ysB[row * 72 + col]);
          }
        }
#pragma unroll
        for (int j = 0; j < 4; ++j) {
          float s1 = t4[0][j] + t4[1][j] + t4[2][j] + t4[3][j];
          float s2 = t4[0][j] * t4[0][j] + t4[1][j] * t4[1][j]
                   + t4[2][j] * t4[2][j] + t4[3][j] * t4[3][j];
          s1 += __shfl_xor(s1, 1); s2 += __shfl_xor(s2, 1);
          s1 += __shfl_xor(s1, 2); s2 += __shfl_xor(s2, 2);
          s1 += __shfl_xor(s1, 4); s2 += __shfl_xor(s2, 4);
          s1 += __shfl_xor(s1, 8); s2 += __shfl_xor(s2, 8);
          float mu = s1 * 0.015625f;
          float rstd = rsqrtf(s2 * 0.015625f - mu * mu + 1e-5f);
          int row = rs * 16 + gq + j;
          u16 o4[4];
          cvt4u((t4[0][j] - mu) * rstd * g2[0 * 16 + lx] + be2[0 * 16 + lx],
                (t4[1][j] - mu) * rstd * g2[1 * 16 + lx] + be2[1 * 16 + lx],
                (t4[2][j] - mu) * rstd * g2[2 * 16 + lx] + be2[2 * 16 + lx],
                (t4[3][j] - mu) * rstd * g2[3 * 16 + lx] + be2[3 * 16 + lx], o4);
#pragma unroll
          for (int f = 0; f < 4; ++f)
            ysB[row * 72 + f * 16 + lx] = o4[f];
        }
      }
      __syncthreads();
    }

    {
      for (int i = tid; i < 256; i += TPB) {
        int f = i >> 6, n = i & 63;
        float v = (f < 3) ? x[(((size_t)b * 3 + f) * 64 + n) * 96 + s] : dcur;
        u16 v16 = f2bf(v);
        xgB[f * 72 + n] = v16;
        zTB[n * 232 + f] = v16;
      }
      const int nb = rs * 16 + gq;
#pragma unroll
      for (int ff = 0; ff < 2; ++ff) {
        int o = (of0 + ff) * 16 + lx;
        float hd0 = sq1 * hreg[ff][0] - sq2 * bf2f(ysB[(nb + 0) * 72 + o]);
        float hd1 = sq1 * hreg[ff][1] - sq2 * bf2f(ysB[(nb + 1) * 72 + o]);
        float hd2 = sq1 * hreg[ff][2] - sq2 * bf2f(ysB[(nb + 2) * 72 + o]);
        float hd3 = sq1 * hreg[ff][3] - sq2 * bf2f(ysB[(nb + 3) * 72 + o]);
        hdreg[ff][0] = hd0; hdreg[ff][1] = hd1; hdreg[ff][2] = hd2; hdreg[ff][3] = hd3;
        unsigned p0 = cvt2(hd0, hd1), p1 = cvt2(hd2, hd3);
        zTB[(nb + 0) * 232 + 4 + o] = (u16)p0;
        zTB[(nb + 1) * 232 + 4 + o] = (u16)(p0 >> 16);
        zTB[(nb + 2) * 232 + 4 + o] = (u16)p1;
        zTB[(nb + 3) * 232 + 4 + o] = (u16)(p1 >> 16);
        uint2 pk; pk.x = p0; pk.y = p1;
        *(uint2*)(xgB + (4 + o) * 72 + nb) = pk;
      }
    }
    __syncthreads();

    for (int t = wv; t < 40; t += 8) {
      int which = (t >= 20) ? 1 : 0;
      int tt = t - which * 20;
      int rw = tt & 3, cf = tt >> 2;
      const u16* A = which ? adj2B : adjB;
      f32x4 acc = {0.f, 0.f, 0.f, 0.f};
      acc = MFMA(fragL(A, rw * 16, 72, 0, lane), fragL(xgB, cf * 16, 72, 0, lane), acc);
      acc = MFMA(fragL(A, rw * 16, 72, 32, lane), fragL(xgB, cf * 16, 72, 32, lane), acc);
      int c = cf * 16 + lx;
      if (c < 68) {
        u16 o4[4]; cvt4u(acc[0], acc[1], acc[2], acc[3], o4);
#pragma unroll
        for (int j = 0; j < 4; ++j)
          zTB[(rw * 16 + gq + j) * 232 + 68 + which * 68 + c] = o4[j];
      }
    }
    __syncthreads();

    {
      f32x4 aU[2] = {{0.f,0.f,0.f,0.f},{0.f,0.f,0.f,0.f}};
      f32x4 aC[2] = {{0.f,0.f,0.f,0.f},{0.f,0.f,0.f,0.f}};
#pragma unroll
      for (int kh = 0; kh < 7; ++kh) {
        bf16x8 a = fragL(zTB, rs * 16, 232, kh * 32, lane);
#pragma unroll
        for (int ff = 0; ff < 2; ++ff) {
          int f = of0 + ff;
          const u16* pu = uwcwB + (size_t)((0 * 4 + f) * 7 + kh) * 512 + lane * 8;
          const u16* pc = uwcwB + (size_t)((1 * 4 + f) * 7 + kh) * 512 + lane * 8;
          aU[ff] = MFMA(a, *(const bf16x8*)pu, aU[ff]);
          aC[ff] = MFMA(a, *(const bf16x8*)pc, aC[ff]);
        }
      }
      const int nb = rs * 16 + gq;
#pragma unroll
      for (int ff = 0; ff < 2; ++ff) {
        int o = (of0 + ff) * 16 + lx;
        float bu_ = ub[o], bc_ = cb[o];
        float4 ov;
#pragma unroll
        for (int j = 0; j < 4; ++j) {
          float u = 1.f / (1.f + __expf(-(aU[ff][j] + bu_)));
          float z = aC[ff][j] + bc_;
          z = fminf(fmaxf(z, -15.f), 15.f);
          float e2 = __expf(2.f * z);
          float cval = (e2 - 1.f) / (e2 + 1.f);
          float hn = u * hdreg[ff][j] + (1.f - u) * cval;
          hreg[ff][j] = hn;
          (&ov.x)[j] = hn;
        }
        unsigned pk0 = cvt2(ov.x, ov.y), pk1 = cvt2(ov.z, ov.w);
        ysB[(nb + 0) * 72 + o] = (u16)pk0;
        ysB[(nb + 1) * 72 + o] = (u16)(pk0 >> 16);
        ysB[(nb + 2) * 72 + o] = (u16)pk1;
        ysB[(nb + 3) * 72 + o] = (u16)(pk1 >> 16);
#pragma unroll
        for (int j = 0; j < 4; ++j)
          out[((size_t)(b * 64 + (nb + j)) * 64 + o) * 96 + s] = (&ov.x)[j];
      }
    }
    __syncthreads();
  }
}

// ws [b][s][d][n] -> out [b][n][d][s]
__global__ __launch_bounds__(256)
void transp_kernel(const float* __restrict__ ws, float* __restrict__ out) {
  int blk = blockIdx.x;
  int b = blk >> 6, o = blk & 63;
  __shared__ float t[96 * 68];
  for (int i = threadIdx.x; i < 96 * 64; i += 256) {
    int ss = i >> 6, n = i & 63;
    t[ss * 68 + n] = ws[((size_t)b * 96 + ss) * 4096 + o * 64 + n];
  }
  __syncthreads();
  for (int i = threadIdx.x; i < 64 * 96; i += 256) {
    int n = i / 96, ss = i - n * 96;
    out[((size_t)(b * 64 + n) * 64 + o) * 96 + ss] = t[ss * 68 + n];
  }
}

extern "C" void kernel_launch(void* const* d_in, const int* in_sizes, int n_in,
                              void* d_out, int out_size, void* d_ws, size_t ws_size,
                              hipStream_t stream)
{
  (void)in_sizes; (void)n_in; (void)out_size;
  const float* x     = (const float*)d_in[0];
  const float* adj   = (const float*)d_in[1];
  const float* h0    = (const float*)d_in[3];
  const float* t_inw = (const float*)d_in[4];
  const float* t_inb = (const float*)d_in[5];
  const float* t_ow  = (const float*)d_in[6];
  const float* t_ob  = (const float*)d_in[7];
  const float* t_w1  = (const float*)d_in[8];
  const float* t_b1  = (const float*)d_in[9];
  const float* t_w2  = (const float*)d_in[10];
  const float* t_b2  = (const float*)d_in[11];
  const float* t_g1  = (const float*)d_in[12];
  const float* t_be1 = (const float*)d_in[13];
  const float* t_g2  = (const float*)d_in[14];
  const float* t_be2 = (const float*)d_in[15];
  const float* uw    = (const float*)d_in[16];
  const float* ub    = (const float*)d_in[17];
  const float* cw    = (const float*)d_in[18];
  const float* cb    = (const float*)d_in[19];
  float* out = (float*)d_out;

  // ws layout: [wsW 98304][wsA2 8192][wsDT 49152][wsX 6291456][stage 201326592]
  const size_t offA2    = 98304;
  const size_t offDT    = 106496;
  const size_t offX     = 155648;
  const size_t offStage = 6447104;
  const size_t stageBytes = (size_t)128 * 96 * 4096 * 4;

  if (ws_size >= offStage + stageBytes) {
    u16*   wsW   = (u16*)d_ws;
    u16*   wsA2  = (u16*)((char*)d_ws + offA2);
    float* wsDT  = (float*)((char*)d_ws + offDT);
    u16*   wsX   = (u16*)((char*)d_ws + offX);
    float* wsOut = (float*)((char*)d_ws + offStage);

    hipLaunchKernelGGL(prep_kernel, dim3(141), dim3(256), 0, stream,
                       t_inw, t_ow, t_w1, t_w2, adj, x, wsW, wsA2, wsDT, wsX);
    hipLaunchKernelGGL(gcrnn_fast, dim3(128), dim3(TPB), 0, stream,
                       adj, h0, t_inb, t_ob, t_b1, t_b2, t_g1, t_be1, t_g2, t_be2,
                       uw, ub, cw, cb, wsW, wsA2, wsDT, wsX, wsOut);
    hipLaunchKernelGGL(transp_kernel, dim3(128 * 64), dim3(256), 0, stream, wsOut, out);
  } else {
    hipLaunchKernelGGL(gcrnn_fb, dim3(128), dim3(TPB), 0, stream,
                       x, adj, h0, t_inw, t_inb, t_ow, t_ob, t_w1, t_b1,
                       t_w2, t_b2, t_g1, t_be1, t_g2, t_be2, uw, ub, cw, cb, out);
  }
}